// Round 1
// baseline (1521.313 us; speedup 1.0000x reference)
//
#include <hip/hip_runtime.h>
#include <stdint.h>

#define N_IMG 2
#define A_NUM 15
#define HH 200
#define WW 200
#define HW 40000          // HH*WW
#define K_TOT 600000      // A_NUM*HW
#define P_PRE 6000
#define R_POST 1000
#define NMS_T 0.7f
#define MIN_SZ 16.0f
#define FSTRIDE 16.0f
#define BBOX_CLIP 4.135166556742356f   // log(1000/16)
#define CAND_CAP 8192
#define NWORDS 94         // ceil(6000/64)

typedef unsigned long long u64;
typedef uint32_t u32;

// Monotone key for non-negative floats (scores are uniform [0,1)).
__device__ __forceinline__ u32 fkey(float s) {
    return __float_as_uint(s) | 0x80000000u;
}

// ---------------- pass 1: 16-bit histogram ----------------
__global__ void k_hist1(const float* __restrict__ sc, u32* __restrict__ hist1) {
    int t = blockIdx.x * 256 + threadIdx.x;
    if (t >= N_IMG * K_TOT) return;
    int n = t / K_TOT;
    u32 u = fkey(sc[t]);
    atomicAdd(&hist1[n * 65536 + (u >> 16)], 1u);
}

// Find the 16-bit bin containing the P_PRE-th largest; cGT = count strictly above.
__global__ void k_find1(const u32* __restrict__ hist1, u32* __restrict__ meta) {
    int n = blockIdx.x;
    const u32* h = hist1 + n * 65536;
    __shared__ u32 part[256];
    int t = threadIdx.x;
    u32 s = 0;
    for (int b = t * 256; b < t * 256 + 256; ++b) s += h[b];
    part[t] = s;
    __syncthreads();
    if (t == 0) {
        u32 cum = 0;
        int seg = 255;
        for (; seg > 0; --seg) {
            if (cum + part[seg] >= P_PRE) break;
            cum += part[seg];
        }
        u32 cgt = cum;
        u32 b16 = (u32)(seg * 256);
        for (int b = seg * 256 + 255; b >= seg * 256; --b) {
            if (cgt + h[b] >= P_PRE) { b16 = (u32)b; break; }
            cgt += h[b];
        }
        meta[n * 16 + 0] = b16;
        meta[n * 16 + 1] = cgt;
    }
}

// ---------------- pass 2: refine 8 more bits ----------------
__global__ void k_hist2(const float* __restrict__ sc, const u32* __restrict__ meta,
                        u32* __restrict__ hist2) {
    int t = blockIdx.x * 256 + threadIdx.x;
    if (t >= N_IMG * K_TOT) return;
    int n = t / K_TOT;
    u32 u = fkey(sc[t]);
    if ((u >> 16) == meta[n * 16 + 0])
        atomicAdd(&hist2[n * 256 + ((u >> 8) & 255u)], 1u);
}

__global__ void k_find2(const u32* __restrict__ hist2, u32* __restrict__ meta) {
    int n = blockIdx.x;
    if (threadIdx.x != 0) return;
    u32 cum = meta[n * 16 + 1];
    u32 b16 = meta[n * 16 + 0];
    const u32* h = hist2 + n * 256;
    for (int b = 255; b >= 0; --b) {
        if (cum + h[b] >= P_PRE) { meta[n * 16 + 2] = (b16 << 8) | (u32)b; break; }
        cum += h[b];
    }
}

// ---------------- compaction of candidates ----------------
__global__ void k_compact(const float* __restrict__ sc, u32* __restrict__ meta,
                          u64* __restrict__ cand) {
    int t = blockIdx.x * 256 + threadIdx.x;
    if (t >= N_IMG * K_TOT) return;
    int n = t / K_TOT;
    int e = t - n * K_TOT;                 // memory order: a*HW + h*WW + w
    u32 u = fkey(sc[t]);
    if ((u >> 8) >= meta[n * 16 + 2]) {
        u32 pos = atomicAdd(&meta[n * 16 + 3], 1u);
        if (pos < CAND_CAP) {
            int a = e / HW;
            int r = e - a * HW;            // h*WW + w
            u32 idx = (u32)(r * A_NUM + a); // logical order (h*W + w)*A + a
            cand[n * CAND_CAP + pos] = ((u64)u << 32) | (u32)(~idx);
        }
    }
}

// ---------------- single-block bitonic sort (desc), take top 6000 ----------------
__global__ void k_sortk(const u64* __restrict__ cand, const u32* __restrict__ meta,
                        u32* __restrict__ topk_idx, float* __restrict__ topk_sc) {
    int n = blockIdx.x;
    extern __shared__ u64 sk[];            // CAND_CAP entries = 64 KiB
    u32 cnt = meta[n * 16 + 3];
    if (cnt > CAND_CAP) cnt = CAND_CAP;
    for (int i = threadIdx.x; i < CAND_CAP; i += 1024)
        sk[i] = (i < (int)cnt) ? cand[n * CAND_CAP + i] : 0ull;
    __syncthreads();
    for (int k = 2; k <= CAND_CAP; k <<= 1) {
        for (int j = k >> 1; j > 0; j >>= 1) {
            for (int i = threadIdx.x; i < CAND_CAP; i += 1024) {
                int ixj = i ^ j;
                if (ixj > i) {
                    u64 a = sk[i], b = sk[ixj];
                    bool desc = ((i & k) == 0);
                    if (desc ? (a < b) : (a > b)) { sk[i] = b; sk[ixj] = a; }
                }
            }
            __syncthreads();
        }
    }
    for (int i = threadIdx.x; i < P_PRE; i += 1024) {
        u64 kk = sk[i];
        u32 idx = ~(u32)(kk & 0xFFFFFFFFull);
        u32 u = (u32)(kk >> 32);
        topk_idx[n * P_PRE + i] = idx;
        topk_sc[n * P_PRE + i] = __uint_as_float(u ^ 0x80000000u);
    }
}

// ---------------- decode + clip + valid ----------------
__global__ void k_decode(const u32* __restrict__ topk_idx,
                         const float* __restrict__ bbox, const float* __restrict__ iminfo,
                         const float* __restrict__ anchors,
                         float* __restrict__ bx1, float* __restrict__ by1,
                         float* __restrict__ bx2, float* __restrict__ by2,
                         u32* __restrict__ bval) {
    int t = blockIdx.x * 256 + threadIdx.x;
    if (t >= N_IMG * P_PRE) return;
    int n = t / P_PRE;
    u32 idx = topk_idx[t];
    int a = (int)(idx % A_NUM);
    int cell = (int)(idx / A_NUM);
    int w = cell % WW, h = cell / WW;
    float ax1 = anchors[a * 4 + 0] + FSTRIDE * (float)w;
    float ay1 = anchors[a * 4 + 1] + FSTRIDE * (float)h;
    float ax2 = anchors[a * 4 + 2] + FSTRIDE * (float)w;
    float ay2 = anchors[a * 4 + 3] + FSTRIDE * (float)h;
    float ws = ax2 - ax1 + 1.0f;
    float hs = ay2 - ay1 + 1.0f;
    float cx = ax1 + 0.5f * ws;
    float cy = ay1 + 0.5f * hs;
    const float* bb = bbox + (size_t)n * 4 * A_NUM * HW + h * WW + w;
    float dx = bb[(4 * a + 0) * HW];
    float dy = bb[(4 * a + 1) * HW];
    float dw = fminf(bb[(4 * a + 2) * HW], BBOX_CLIP);
    float dh = fminf(bb[(4 * a + 3) * HW], BBOX_CLIP);
    float pcx = dx * ws + cx, pcy = dy * hs + cy;
    float pw = expf(dw) * ws, ph = expf(dh) * hs;
    float x1 = pcx - 0.5f * pw;
    float y1 = pcy - 0.5f * ph;
    float x2 = pcx + 0.5f * pw - 1.0f;
    float y2 = pcy + 0.5f * ph - 1.0f;
    float im_h = iminfo[n * 3 + 0], im_w = iminfo[n * 3 + 1], iscale = iminfo[n * 3 + 2];
    x1 = fminf(fmaxf(x1, 0.0f), im_w - 1.0f);
    y1 = fminf(fmaxf(y1, 0.0f), im_h - 1.0f);
    x2 = fminf(fmaxf(x2, 0.0f), im_w - 1.0f);
    y2 = fminf(fmaxf(y2, 0.0f), im_h - 1.0f);
    float wss = x2 - x1 + 1.0f, hss = y2 - y1 + 1.0f;
    float xc = x1 + wss * 0.5f, yc = y1 + hss * 0.5f;
    float ms = MIN_SZ * iscale;
    bool valid = (wss >= ms) && (hss >= ms) && (xc < im_w) && (yc < im_h);
    bx1[t] = x1; by1[t] = y1; bx2[t] = x2; by2[t] = y2;
    bval[t] = valid ? 1u : 0u;
}

// ---------------- stable partition (valid first, order preserved) ----------------
__global__ void k_partition(const float* __restrict__ bx1, const float* __restrict__ by1,
                            const float* __restrict__ bx2, const float* __restrict__ by2,
                            const float* __restrict__ bsc, const u32* __restrict__ bval,
                            float* __restrict__ sx1, float* __restrict__ sy1,
                            float* __restrict__ sx2, float* __restrict__ sy2,
                            float* __restrict__ ssc, u32* __restrict__ meta) {
    int n = blockIdx.x;
    int t = threadIdx.x;
    __shared__ u32 part[1024];
    int base = t * 6;
    u32 cnt = 0;
    if (base < P_PRE)
        for (int e = 0; e < 6; ++e) cnt += bval[n * P_PRE + base + e];
    part[t] = cnt;
    __syncthreads();
    for (int off = 1; off < 1024; off <<= 1) {
        u32 v = part[t];
        u32 add = (t >= off) ? part[t - off] : 0u;
        __syncthreads();
        part[t] = v + add;
        __syncthreads();
    }
    u32 nv = part[1023];
    u32 excl = (t == 0) ? 0u : part[t - 1];
    if (t == 0) meta[n * 16 + 4] = nv;
    if (base < P_PRE) {
        u32 vseen = excl;
        for (int e = 0; e < 6; ++e) {
            int g = base + e;
            int src = n * P_PRE + g;
            u32 dst;
            if (bval[src]) { dst = vseen; vseen++; }
            else { dst = nv + (u32)g - vseen; }
            int d = n * P_PRE + (int)dst;
            sx1[d] = bx1[src]; sy1[d] = by1[src];
            sx2[d] = bx2[src]; sy2[d] = by2[src];
            ssc[d] = bsc[src];
        }
    }
}

// ---------------- NMS suppression bitmask (upper triangle) ----------------
__global__ void k_mask(const float* __restrict__ sx1, const float* __restrict__ sy1,
                       const float* __restrict__ sx2, const float* __restrict__ sy2,
                       const u32* __restrict__ meta, u64* __restrict__ mask) {
    int t = blockIdx.x * 256 + threadIdx.x;
    if (t >= N_IMG * P_PRE * NWORDS) return;
    int n = t / (P_PRE * NWORDS);
    int rem = t - n * (P_PRE * NWORDS);
    int i = rem / NWORDS;
    int c = rem - i * NWORDS;
    u32 nv = meta[n * 16 + 4];
    if ((u32)i >= nv) return;              // invalid rows never suppress / never read
    const float* px1 = sx1 + n * P_PRE;
    const float* py1 = sy1 + n * P_PRE;
    const float* px2 = sx2 + n * P_PRE;
    const float* py2 = sy2 + n * P_PRE;
    float X1 = px1[i], Y1 = py1[i], X2 = px2[i], Y2 = py2[i];
    float ar = (X2 - X1 + 1.0f) * (Y2 - Y1 + 1.0f);
    int jbase = c * 64;
    int jend = min(jbase + 64, P_PRE);
    u64 m = 0;
    for (int j = max(jbase, i + 1); j < jend; ++j) {
        float xx1 = fmaxf(X1, px1[j]);
        float yy1 = fmaxf(Y1, py1[j]);
        float xx2 = fminf(X2, px2[j]);
        float yy2 = fminf(Y2, py2[j]);
        float iw = fmaxf(xx2 - xx1 + 1.0f, 0.0f);
        float ih = fmaxf(yy2 - yy1 + 1.0f, 0.0f);
        float inter = iw * ih;
        float arj = (px2[j] - px1[j] + 1.0f) * (py2[j] - py1[j] + 1.0f);
        float iou = inter / (ar + arj - inter);
        if (iou > NMS_T) m |= 1ull << (j - jbase);
    }
    mask[t] = m;
}

// ---------------- sequential greedy NMS scan (1 wave per image) ----------------
__global__ void k_scan(const float* __restrict__ sx1, const float* __restrict__ sy1,
                       const float* __restrict__ sx2, const float* __restrict__ sy2,
                       const u64* __restrict__ mask, u32* __restrict__ meta,
                       u32* __restrict__ keptList) {
    int n = blockIdx.x;
    int lane = threadIdx.x;                 // 64 threads = 1 wave
    __shared__ u32 kidx[R_POST];
    u32 nv = meta[n * 16 + 4];
    const float* px1 = sx1 + n * P_PRE;
    const float* py1 = sy1 + n * P_PRE;
    const float* px2 = sx2 + n * P_PRE;
    const float* py2 = sy2 + n * P_PRE;
    int kept = 0;
    bool done = false;
    for (int c = 0; c < NWORDS && !done; ++c) {
        __syncthreads();
        int jbase = c * 64;
        int j = jbase + lane;
        bool inr = j < P_PRE;
        float X1 = 0.f, Y1 = 0.f, X2 = 0.f, Y2 = 0.f, ar = 0.f;
        if (inr) {
            X1 = px1[j]; Y1 = py1[j]; X2 = px2[j]; Y2 = py2[j];
            ar = (X2 - X1 + 1.0f) * (Y2 - Y1 + 1.0f);
        }
        u64 cur = __ballot((u32)j >= nv);   // invalid/oob start removed
        // cross-chunk suppression from previously-kept rows via mask words
        u64 acc = 0;
        for (int k = lane; k < kept; k += 64)
            acc |= mask[(size_t)((n * P_PRE + (int)kidx[k]) * NWORDS + c)];
        #pragma unroll
        for (int off = 32; off > 0; off >>= 1)
            acc |= __shfl_xor(acc, off);
        cur |= acc;
        // serial within-chunk scan; IoU on the fly (boxes live in lane registers)
        while (true) {
            u64 inv = ~cur;
            if (inv == 0ull) break;
            int b = (int)__builtin_ctzll(inv);
            int jb = jbase + b;
            if (lane == 0) {
                kidx[kept] = (u32)jb;
                keptList[n * R_POST + kept] = (u32)jb;
            }
            kept++;
            if (kept >= R_POST) { done = true; break; }
            float bX1 = __shfl(X1, b);
            float bY1 = __shfl(Y1, b);
            float bX2 = __shfl(X2, b);
            float bY2 = __shfl(Y2, b);
            float bar = __shfl(ar, b);
            bool sup = false;
            if (inr && lane > b) {
                float xx1 = fmaxf(bX1, X1);
                float yy1 = fmaxf(bY1, Y1);
                float xx2 = fminf(bX2, X2);
                float yy2 = fminf(bY2, Y2);
                float iw = fmaxf(xx2 - xx1 + 1.0f, 0.0f);
                float ih = fmaxf(yy2 - yy1 + 1.0f, 0.0f);
                float inter = iw * ih;
                float iou = inter / (bar + ar - inter);
                sup = iou > NMS_T;
            }
            cur |= __ballot(sup);
            cur |= (1ull << b);
        }
    }
    if (lane == 0) meta[n * 16 + 5] = (u32)kept;
}

// ---------------- final output ----------------
__global__ void k_out(const float* __restrict__ sx1, const float* __restrict__ sy1,
                      const float* __restrict__ sx2, const float* __restrict__ sy2,
                      const float* __restrict__ ssc, const u32* __restrict__ keptList,
                      const u32* __restrict__ meta, float* __restrict__ out) {
    int r = blockIdx.x * 256 + threadIdx.x;
    if (r >= N_IMG * R_POST) return;
    int n = r / R_POST, k = r - n * R_POST;
    float* o = out + (size_t)r * 6;
    o[0] = (float)n;                        // batch index is NOT masked in the reference
    if ((u32)k < meta[n * 16 + 5]) {
        int i = n * P_PRE + (int)keptList[n * R_POST + k];
        o[1] = sx1[i]; o[2] = sy1[i]; o[3] = sx2[i]; o[4] = sy2[i]; o[5] = ssc[i];
    } else {
        o[1] = 0.0f; o[2] = 0.0f; o[3] = 0.0f; o[4] = 0.0f; o[5] = 0.0f;
    }
}

extern "C" void kernel_launch(void* const* d_in, const int* in_sizes, int n_in,
                              void* d_out, int out_size, void* d_ws, size_t ws_size,
                              hipStream_t stream) {
    const float* scores  = (const float*)d_in[0];
    const float* bbox    = (const float*)d_in[1];
    const float* iminfo  = (const float*)d_in[2];
    const float* anchors = (const float*)d_in[3];
    float* out = (float*)d_out;

    char* ws = (char*)d_ws;
    size_t off = 0;
    u32* hist1 = (u32*)(ws + off); off += (size_t)N_IMG * 65536 * 4;   // 524288
    u32* hist2 = (u32*)(ws + off); off += (size_t)N_IMG * 256 * 4;     // 2048
    u32* meta  = (u32*)(ws + off); off += (size_t)N_IMG * 16 * 4;      // 128
    size_t zeroBytes = off;                                            // 526464
    u64* cand      = (u64*)(ws + off);   off += (size_t)N_IMG * CAND_CAP * 8;
    u32* topk_idx  = (u32*)(ws + off);   off += (size_t)N_IMG * P_PRE * 4;
    float* topk_sc = (float*)(ws + off); off += (size_t)N_IMG * P_PRE * 4;
    float* bx1 = (float*)(ws + off); off += (size_t)N_IMG * P_PRE * 4;
    float* by1 = (float*)(ws + off); off += (size_t)N_IMG * P_PRE * 4;
    float* bx2 = (float*)(ws + off); off += (size_t)N_IMG * P_PRE * 4;
    float* by2 = (float*)(ws + off); off += (size_t)N_IMG * P_PRE * 4;
    u32* bval  = (u32*)(ws + off);   off += (size_t)N_IMG * P_PRE * 4;
    float* sx1 = (float*)(ws + off); off += (size_t)N_IMG * P_PRE * 4;
    float* sy1 = (float*)(ws + off); off += (size_t)N_IMG * P_PRE * 4;
    float* sx2 = (float*)(ws + off); off += (size_t)N_IMG * P_PRE * 4;
    float* sy2 = (float*)(ws + off); off += (size_t)N_IMG * P_PRE * 4;
    float* ssc = (float*)(ws + off); off += (size_t)N_IMG * P_PRE * 4;
    u32* keptList = (u32*)(ws + off); off += (size_t)N_IMG * R_POST * 4;
    u64* mask = (u64*)(ws + off);     off += (size_t)N_IMG * P_PRE * NWORDS * 8;
    (void)ws_size; (void)in_sizes; (void)n_in; (void)out_size;

    hipMemsetAsync(d_ws, 0, zeroBytes, stream);

    int gridK = (N_IMG * K_TOT + 255) / 256;               // 4688
    k_hist1<<<gridK, 256, 0, stream>>>(scores, hist1);
    k_find1<<<N_IMG, 256, 0, stream>>>(hist1, meta);
    k_hist2<<<gridK, 256, 0, stream>>>(scores, meta, hist2);
    k_find2<<<N_IMG, 64, 0, stream>>>(hist2, meta);
    k_compact<<<gridK, 256, 0, stream>>>(scores, meta, cand);
    k_sortk<<<N_IMG, 1024, CAND_CAP * sizeof(u64), stream>>>(cand, meta, topk_idx, topk_sc);
    k_decode<<<(N_IMG * P_PRE + 255) / 256, 256, 0, stream>>>(topk_idx, bbox, iminfo, anchors,
                                                              bx1, by1, bx2, by2, bval);
    k_partition<<<N_IMG, 1024, 0, stream>>>(bx1, by1, bx2, by2, topk_sc, bval,
                                            sx1, sy1, sx2, sy2, ssc, meta);
    int gridM = (N_IMG * P_PRE * NWORDS + 255) / 256;      // 4407
    k_mask<<<gridM, 256, 0, stream>>>(sx1, sy1, sx2, sy2, meta, mask);
    k_scan<<<N_IMG, 64, 0, stream>>>(sx1, sy1, sx2, sy2, mask, meta, keptList);
    k_out<<<(N_IMG * R_POST + 255) / 256, 256, 0, stream>>>(sx1, sy1, sx2, sy2, ssc,
                                                            keptList, meta, out);
}

// Round 2
// 663.226 us; speedup vs baseline: 2.2938x; 2.2938x over previous
//
#include <hip/hip_runtime.h>
#include <stdint.h>

#define N_IMG 2
#define A_NUM 15
#define HH 200
#define WW 200
#define HW 40000          // HH*WW
#define K_TOT 600000      // A_NUM*HW
#define K_TOT4 150000     // K_TOT/4
#define P_PRE 6000
#define R_POST 1000
#define NMS_T 0.7f
#define MIN_SZ 16.0f
#define FSTRIDE 16.0f
#define BBOX_CLIP 4.135166556742356f   // log(1000/16)
#define CAND_CAP 8192
#define NWORDS 94         // ceil(6000/64)
#define BINS 4096

typedef unsigned long long u64;
typedef uint32_t u32;

// Monotone key for non-negative floats (scores are uniform [0,1)).
__device__ __forceinline__ u32 fkey(float s) {
    return __float_as_uint(s) | 0x80000000u;
}

// ---------------- pass A: 12-bit histogram, LDS-privatized ----------------
// grid (64, N_IMG), 256 threads; grid-stride over float4s of one image.
__global__ void k_histA(const float* __restrict__ sc, u32* __restrict__ histA) {
    int n = blockIdx.y;
    __shared__ u32 h[BINS];
    for (int i = threadIdx.x; i < BINS; i += 256) h[i] = 0;
    __syncthreads();
    const float4* s4 = (const float4*)(sc + (size_t)n * K_TOT);
    for (int i = blockIdx.x * 256 + threadIdx.x; i < K_TOT4; i += 64 * 256) {
        float4 v = s4[i];
        atomicAdd(&h[fkey(v.x) >> 20], 1u);
        atomicAdd(&h[fkey(v.y) >> 20], 1u);
        atomicAdd(&h[fkey(v.z) >> 20], 1u);
        atomicAdd(&h[fkey(v.w) >> 20], 1u);
    }
    __syncthreads();
    for (int i = threadIdx.x; i < BINS; i += 256) {
        u32 v = h[i];
        if (v) atomicAdd(&histA[n * BINS + i], v);
    }
}

// Find 12-bit bin containing the P_PRE-th largest; cgt = count strictly above.
__global__ void k_findA(const u32* __restrict__ histA, u32* __restrict__ meta) {
    int n = blockIdx.x;
    const u32* h = histA + n * BINS;
    __shared__ u32 part[256];
    int t = threadIdx.x;
    u32 s = 0;
    for (int b = t * 16; b < t * 16 + 16; ++b) s += h[b];
    part[t] = s;
    __syncthreads();
    if (t == 0) {
        u32 cum = 0;
        int seg = 255;
        for (; seg > 0; --seg) {
            if (cum + part[seg] >= P_PRE) break;
            cum += part[seg];
        }
        u32 cgt = cum;
        int bA = seg * 16;
        for (int b = seg * 16 + 15; b >= seg * 16; --b) {
            if (cgt + h[b] >= P_PRE) { bA = b; break; }
            cgt += h[b];
        }
        meta[n * 16 + 0] = (u32)bA;
        meta[n * 16 + 1] = cgt;
    }
}

// ---------------- pass B: refine next 12 bits (LDS-privatized) ----------------
__global__ void k_histB(const float* __restrict__ sc, const u32* __restrict__ meta,
                        u32* __restrict__ histB) {
    int n = blockIdx.y;
    __shared__ u32 h[BINS];
    for (int i = threadIdx.x; i < BINS; i += 256) h[i] = 0;
    __syncthreads();
    u32 bA = meta[n * 16 + 0];
    const float4* s4 = (const float4*)(sc + (size_t)n * K_TOT);
    for (int i = blockIdx.x * 256 + threadIdx.x; i < K_TOT4; i += 64 * 256) {
        float4 v = s4[i];
        u32 k0 = fkey(v.x), k1 = fkey(v.y), k2 = fkey(v.z), k3 = fkey(v.w);
        if ((k0 >> 20) == bA) atomicAdd(&h[(k0 >> 8) & 0xFFFu], 1u);
        if ((k1 >> 20) == bA) atomicAdd(&h[(k1 >> 8) & 0xFFFu], 1u);
        if ((k2 >> 20) == bA) atomicAdd(&h[(k2 >> 8) & 0xFFFu], 1u);
        if ((k3 >> 20) == bA) atomicAdd(&h[(k3 >> 8) & 0xFFFu], 1u);
    }
    __syncthreads();
    for (int i = threadIdx.x; i < BINS; i += 256) {
        u32 v = h[i];
        if (v) atomicAdd(&histB[n * BINS + i], v);
    }
}

__global__ void k_findB(const u32* __restrict__ histB, u32* __restrict__ meta) {
    int n = blockIdx.x;
    const u32* h = histB + n * BINS;
    __shared__ u32 part[256];
    int t = threadIdx.x;
    u32 s = 0;
    for (int b = t * 16; b < t * 16 + 16; ++b) s += h[b];
    part[t] = s;
    __syncthreads();
    if (t == 0) {
        u32 cum = meta[n * 16 + 1];
        int seg = 255;
        for (; seg > 0; --seg) {
            if (cum + part[seg] >= P_PRE) break;
            cum += part[seg];
        }
        int bB = seg * 16;
        for (int b = seg * 16 + 15; b >= seg * 16; --b) {
            if (cum + h[b] >= P_PRE) { bB = b; break; }
            cum += h[b];
        }
        // 24-bit prefix threshold, identical semantics to round-0 meta[2]
        meta[n * 16 + 2] = (meta[n * 16 + 0] << 12) | (u32)bB;
    }
}

// ---------------- compaction of candidates ----------------
// grid (ceil(K_TOT4/256), N_IMG)
__global__ void k_compact(const float* __restrict__ sc, u32* __restrict__ meta,
                          u64* __restrict__ cand) {
    int n = blockIdx.y;
    int i4 = blockIdx.x * 256 + threadIdx.x;
    if (i4 >= K_TOT4) return;
    u32 thr = meta[n * 16 + 2];
    const float4* s4 = (const float4*)(sc + (size_t)n * K_TOT);
    float4 v = s4[i4];
    float vv[4] = {v.x, v.y, v.z, v.w};
    #pragma unroll
    for (int e = 0; e < 4; ++e) {
        u32 u = fkey(vv[e]);
        if ((u >> 8) >= thr) {
            u32 pos = atomicAdd(&meta[n * 16 + 3], 1u);
            if (pos < CAND_CAP) {
                int el = i4 * 4 + e;               // memory order: a*HW + h*WW + w
                int a = el / HW;
                int r = el - a * HW;               // h*WW + w
                u32 idx = (u32)(r * A_NUM + a);    // logical order (h*W + w)*A + a
                cand[n * CAND_CAP + pos] = ((u64)u << 32) | (u32)(~idx);
            }
        }
    }
}

// ---------------- single-block bitonic sort (desc), take top 6000 ----------------
__global__ void k_sortk(const u64* __restrict__ cand, const u32* __restrict__ meta,
                        u32* __restrict__ topk_idx, float* __restrict__ topk_sc) {
    int n = blockIdx.x;
    extern __shared__ u64 sk[];            // CAND_CAP entries = 64 KiB
    u32 cnt = meta[n * 16 + 3];
    if (cnt > CAND_CAP) cnt = CAND_CAP;
    for (int i = threadIdx.x; i < CAND_CAP; i += 1024)
        sk[i] = (i < (int)cnt) ? cand[n * CAND_CAP + i] : 0ull;
    __syncthreads();
    for (int k = 2; k <= CAND_CAP; k <<= 1) {
        for (int j = k >> 1; j > 0; j >>= 1) {
            for (int i = threadIdx.x; i < CAND_CAP; i += 1024) {
                int ixj = i ^ j;
                if (ixj > i) {
                    u64 a = sk[i], b = sk[ixj];
                    bool desc = ((i & k) == 0);
                    if (desc ? (a < b) : (a > b)) { sk[i] = b; sk[ixj] = a; }
                }
            }
            __syncthreads();
        }
    }
    for (int i = threadIdx.x; i < P_PRE; i += 1024) {
        u64 kk = sk[i];
        u32 idx = ~(u32)(kk & 0xFFFFFFFFull);
        u32 u = (u32)(kk >> 32);
        topk_idx[n * P_PRE + i] = idx;
        topk_sc[n * P_PRE + i] = __uint_as_float(u ^ 0x80000000u);
    }
}

// ---------------- decode + clip + valid ----------------
__global__ void k_decode(const u32* __restrict__ topk_idx,
                         const float* __restrict__ bbox, const float* __restrict__ iminfo,
                         const float* __restrict__ anchors,
                         float4* __restrict__ bbox4, u32* __restrict__ bval) {
    int t = blockIdx.x * 256 + threadIdx.x;
    if (t >= N_IMG * P_PRE) return;
    int n = t / P_PRE;
    u32 idx = topk_idx[t];
    int a = (int)(idx % A_NUM);
    int cell = (int)(idx / A_NUM);
    int w = cell % WW, h = cell / WW;
    float ax1 = anchors[a * 4 + 0] + FSTRIDE * (float)w;
    float ay1 = anchors[a * 4 + 1] + FSTRIDE * (float)h;
    float ax2 = anchors[a * 4 + 2] + FSTRIDE * (float)w;
    float ay2 = anchors[a * 4 + 3] + FSTRIDE * (float)h;
    float ws = ax2 - ax1 + 1.0f;
    float hs = ay2 - ay1 + 1.0f;
    float cx = ax1 + 0.5f * ws;
    float cy = ay1 + 0.5f * hs;
    const float* bb = bbox + (size_t)n * 4 * A_NUM * HW + h * WW + w;
    float dx = bb[(4 * a + 0) * HW];
    float dy = bb[(4 * a + 1) * HW];
    float dw = fminf(bb[(4 * a + 2) * HW], BBOX_CLIP);
    float dh = fminf(bb[(4 * a + 3) * HW], BBOX_CLIP);
    float pcx = dx * ws + cx, pcy = dy * hs + cy;
    float pw = expf(dw) * ws, ph = expf(dh) * hs;
    float x1 = pcx - 0.5f * pw;
    float y1 = pcy - 0.5f * ph;
    float x2 = pcx + 0.5f * pw - 1.0f;
    float y2 = pcy + 0.5f * ph - 1.0f;
    float im_h = iminfo[n * 3 + 0], im_w = iminfo[n * 3 + 1], iscale = iminfo[n * 3 + 2];
    x1 = fminf(fmaxf(x1, 0.0f), im_w - 1.0f);
    y1 = fminf(fmaxf(y1, 0.0f), im_h - 1.0f);
    x2 = fminf(fmaxf(x2, 0.0f), im_w - 1.0f);
    y2 = fminf(fmaxf(y2, 0.0f), im_h - 1.0f);
    float wss = x2 - x1 + 1.0f, hss = y2 - y1 + 1.0f;
    float xc = x1 + wss * 0.5f, yc = y1 + hss * 0.5f;
    float ms = MIN_SZ * iscale;
    bool valid = (wss >= ms) && (hss >= ms) && (xc < im_w) && (yc < im_h);
    float4 b; b.x = x1; b.y = y1; b.z = x2; b.w = y2;
    bbox4[t] = b;
    bval[t] = valid ? 1u : 0u;
}

// ---------------- stable partition (valid first, order preserved) ----------------
__global__ void k_partition(const float4* __restrict__ bbox4,
                            const float* __restrict__ bsc, const u32* __restrict__ bval,
                            float4* __restrict__ sbox, float* __restrict__ ssc,
                            u32* __restrict__ meta) {
    int n = blockIdx.x;
    int t = threadIdx.x;
    __shared__ u32 part[1024];
    int base = t * 6;
    u32 cnt = 0;
    if (base < P_PRE)
        for (int e = 0; e < 6; ++e) cnt += bval[n * P_PRE + base + e];
    part[t] = cnt;
    __syncthreads();
    for (int off = 1; off < 1024; off <<= 1) {
        u32 v = part[t];
        u32 add = (t >= off) ? part[t - off] : 0u;
        __syncthreads();
        part[t] = v + add;
        __syncthreads();
    }
    u32 nv = part[1023];
    u32 excl = (t == 0) ? 0u : part[t - 1];
    if (t == 0) meta[n * 16 + 4] = nv;
    if (base < P_PRE) {
        u32 vseen = excl;
        for (int e = 0; e < 6; ++e) {
            int g = base + e;
            int src = n * P_PRE + g;
            u32 dst;
            if (bval[src]) { dst = vseen; vseen++; }
            else { dst = nv + (u32)g - vseen; }
            int d = n * P_PRE + (int)dst;
            sbox[d] = bbox4[src];
            ssc[d] = bsc[src];
        }
    }
}

// ---------------- NMS suppression bitmask (upper triangle) ----------------
__global__ void k_mask(const float4* __restrict__ sbox,
                       const u32* __restrict__ meta, u64* __restrict__ mask) {
    int t = blockIdx.x * 256 + threadIdx.x;
    if (t >= N_IMG * P_PRE * NWORDS) return;
    int n = t / (P_PRE * NWORDS);
    int rem = t - n * (P_PRE * NWORDS);
    int i = rem / NWORDS;
    int c = rem - i * NWORDS;
    u32 nv = meta[n * 16 + 4];
    if ((u32)i >= nv) return;              // invalid rows never suppress / never read
    const float4* pb = sbox + n * P_PRE;
    float4 bi = pb[i];
    float ar = (bi.z - bi.x + 1.0f) * (bi.w - bi.y + 1.0f);
    int jbase = c * 64;
    int jend = min(jbase + 64, P_PRE);
    u64 m = 0;
    for (int j = max(jbase, i + 1); j < jend; ++j) {
        float4 bj = pb[j];
        float xx1 = fmaxf(bi.x, bj.x);
        float yy1 = fmaxf(bi.y, bj.y);
        float xx2 = fminf(bi.z, bj.z);
        float yy2 = fminf(bi.w, bj.w);
        float iw = fmaxf(xx2 - xx1 + 1.0f, 0.0f);
        float ih = fmaxf(yy2 - yy1 + 1.0f, 0.0f);
        float inter = iw * ih;
        float arj = (bj.z - bj.x + 1.0f) * (bj.w - bj.y + 1.0f);
        float iou = inter / (ar + arj - inter);
        if (iou > NMS_T) m |= 1ull << (j - jbase);
    }
    mask[t] = m;
}

// ---------------- sequential greedy NMS scan (1 wave per image) ----------------
__global__ void k_scan(const float4* __restrict__ sbox,
                       const u64* __restrict__ mask, u32* __restrict__ meta,
                       u32* __restrict__ keptList) {
    int n = blockIdx.x;
    int lane = threadIdx.x;                 // 64 threads = 1 wave
    __shared__ u32 kidx[R_POST];
    u32 nv = meta[n * 16 + 4];
    const float4* pb = sbox + n * P_PRE;
    int kept = 0;
    bool done = false;
    for (int c = 0; c < NWORDS && !done; ++c) {
        __syncthreads();
        int jbase = c * 64;
        int j = jbase + lane;
        bool inr = j < P_PRE;
        float X1 = 0.f, Y1 = 0.f, X2 = 0.f, Y2 = 0.f, ar = 0.f;
        if (inr) {
            float4 b = pb[j];
            X1 = b.x; Y1 = b.y; X2 = b.z; Y2 = b.w;
            ar = (X2 - X1 + 1.0f) * (Y2 - Y1 + 1.0f);
        }
        u64 cur = __ballot((u32)j >= nv);   // invalid/oob start removed
        // cross-chunk suppression from previously-kept rows via mask words
        u64 acc = 0;
        for (int k = lane; k < kept; k += 64)
            acc |= mask[(size_t)((n * P_PRE + (int)kidx[k]) * NWORDS + c)];
        #pragma unroll
        for (int off = 32; off > 0; off >>= 1)
            acc |= __shfl_xor(acc, off);
        cur |= acc;
        // serial within-chunk scan; IoU on the fly (boxes live in lane registers)
        while (true) {
            u64 inv = ~cur;
            if (inv == 0ull) break;
            int b = (int)__builtin_ctzll(inv);
            int jb = jbase + b;
            if (lane == 0) {
                kidx[kept] = (u32)jb;
                keptList[n * R_POST + kept] = (u32)jb;
            }
            kept++;
            if (kept >= R_POST) { done = true; break; }
            float bX1 = __shfl(X1, b);
            float bY1 = __shfl(Y1, b);
            float bX2 = __shfl(X2, b);
            float bY2 = __shfl(Y2, b);
            float bar = __shfl(ar, b);
            bool sup = false;
            if (inr && lane > b) {
                float xx1 = fmaxf(bX1, X1);
                float yy1 = fmaxf(bY1, Y1);
                float xx2 = fminf(bX2, X2);
                float yy2 = fminf(bY2, Y2);
                float iw = fmaxf(xx2 - xx1 + 1.0f, 0.0f);
                float ih = fmaxf(yy2 - yy1 + 1.0f, 0.0f);
                float inter = iw * ih;
                float iou = inter / (bar + ar - inter);
                sup = iou > NMS_T;
            }
            cur |= __ballot(sup);
            cur |= (1ull << b);
        }
    }
    if (lane == 0) meta[n * 16 + 5] = (u32)kept;
}

// ---------------- final output ----------------
__global__ void k_out(const float4* __restrict__ sbox, const float* __restrict__ ssc,
                      const u32* __restrict__ keptList,
                      const u32* __restrict__ meta, float* __restrict__ out) {
    int r = blockIdx.x * 256 + threadIdx.x;
    if (r >= N_IMG * R_POST) return;
    int n = r / R_POST, k = r - n * R_POST;
    float* o = out + (size_t)r * 6;
    o[0] = (float)n;                        // batch index is NOT masked in the reference
    if ((u32)k < meta[n * 16 + 5]) {
        int i = n * P_PRE + (int)keptList[n * R_POST + k];
        float4 b = sbox[i];
        o[1] = b.x; o[2] = b.y; o[3] = b.z; o[4] = b.w; o[5] = ssc[i];
    } else {
        o[1] = 0.0f; o[2] = 0.0f; o[3] = 0.0f; o[4] = 0.0f; o[5] = 0.0f;
    }
}

extern "C" void kernel_launch(void* const* d_in, const int* in_sizes, int n_in,
                              void* d_out, int out_size, void* d_ws, size_t ws_size,
                              hipStream_t stream) {
    const float* scores  = (const float*)d_in[0];
    const float* bbox    = (const float*)d_in[1];
    const float* iminfo  = (const float*)d_in[2];
    const float* anchors = (const float*)d_in[3];
    float* out = (float*)d_out;

    char* ws = (char*)d_ws;
    size_t off = 0;
    u32* histA = (u32*)(ws + off); off += (size_t)N_IMG * BINS * 4;    // 32768
    u32* histB = (u32*)(ws + off); off += (size_t)N_IMG * BINS * 4;    // 32768
    u32* meta  = (u32*)(ws + off); off += (size_t)N_IMG * 16 * 4;      // 128
    size_t zeroBytes = off;                                            // 65664
    u64* cand      = (u64*)(ws + off);   off += (size_t)N_IMG * CAND_CAP * 8;
    u32* topk_idx  = (u32*)(ws + off);   off += (size_t)N_IMG * P_PRE * 4;
    float* topk_sc = (float*)(ws + off); off += (size_t)N_IMG * P_PRE * 4;
    float4* bbox4  = (float4*)(ws + off); off += (size_t)N_IMG * P_PRE * 16;
    u32* bval  = (u32*)(ws + off);   off += (size_t)N_IMG * P_PRE * 4;
    float4* sbox = (float4*)(ws + off); off += (size_t)N_IMG * P_PRE * 16;
    float* ssc = (float*)(ws + off); off += (size_t)N_IMG * P_PRE * 4;
    u32* keptList = (u32*)(ws + off); off += (size_t)N_IMG * R_POST * 4;
    u64* mask = (u64*)(ws + off);     off += (size_t)N_IMG * P_PRE * NWORDS * 8;
    (void)ws_size; (void)in_sizes; (void)n_in; (void)out_size;

    hipMemsetAsync(d_ws, 0, zeroBytes, stream);

    dim3 gHist(64, N_IMG);
    k_histA<<<gHist, 256, 0, stream>>>(scores, histA);
    k_findA<<<N_IMG, 256, 0, stream>>>(histA, meta);
    k_histB<<<gHist, 256, 0, stream>>>(scores, meta, histB);
    k_findB<<<N_IMG, 256, 0, stream>>>(histB, meta);
    dim3 gComp((K_TOT4 + 255) / 256, N_IMG);
    k_compact<<<gComp, 256, 0, stream>>>(scores, meta, cand);
    k_sortk<<<N_IMG, 1024, CAND_CAP * sizeof(u64), stream>>>(cand, meta, topk_idx, topk_sc);
    k_decode<<<(N_IMG * P_PRE + 255) / 256, 256, 0, stream>>>(topk_idx, bbox, iminfo, anchors,
                                                              bbox4, bval);
    k_partition<<<N_IMG, 1024, 0, stream>>>(bbox4, topk_sc, bval, sbox, ssc, meta);
    int gridM = (N_IMG * P_PRE * NWORDS + 255) / 256;      // 4407
    k_mask<<<gridM, 256, 0, stream>>>(sbox, meta, mask);
    k_scan<<<N_IMG, 64, 0, stream>>>(sbox, mask, meta, keptList);
    k_out<<<(N_IMG * R_POST + 255) / 256, 256, 0, stream>>>(sbox, ssc, keptList, meta, out);
}

// Round 3
// 536.655 us; speedup vs baseline: 2.8348x; 1.2359x over previous
//
#include <hip/hip_runtime.h>
#include <stdint.h>

#define N_IMG 2
#define A_NUM 15
#define HH 200
#define WW 200
#define HW 40000          // HH*WW
#define K_TOT 600000      // A_NUM*HW
#define K_TOT4 150000     // K_TOT/4
#define P_PRE 6000
#define R_POST 1000
#define NMS_T 0.7f
#define MIN_SZ 16.0f
#define FSTRIDE 16.0f
#define BBOX_CLIP 4.135166556742356f   // log(1000/16)
#define CAND_CAP 8192
#define NWORDS 94         // ceil(6000/64)
#define BINS 4096

typedef unsigned long long u64;
typedef uint32_t u32;

// Monotone key for non-negative floats (scores are uniform [0,1)).
__device__ __forceinline__ u32 fkey(float s) {
    return __float_as_uint(s) | 0x80000000u;
}

// ---------------- pass A: 12-bit histogram, LDS-privatized ----------------
__global__ void k_histA(const float* __restrict__ sc, u32* __restrict__ histA) {
    int n = blockIdx.y;
    __shared__ u32 h[BINS];
    for (int i = threadIdx.x; i < BINS; i += 256) h[i] = 0;
    __syncthreads();
    const float4* s4 = (const float4*)(sc + (size_t)n * K_TOT);
    for (int i = blockIdx.x * 256 + threadIdx.x; i < K_TOT4; i += 64 * 256) {
        float4 v = s4[i];
        atomicAdd(&h[fkey(v.x) >> 20], 1u);
        atomicAdd(&h[fkey(v.y) >> 20], 1u);
        atomicAdd(&h[fkey(v.z) >> 20], 1u);
        atomicAdd(&h[fkey(v.w) >> 20], 1u);
    }
    __syncthreads();
    for (int i = threadIdx.x; i < BINS; i += 256) {
        u32 v = h[i];
        if (v) atomicAdd(&histA[n * BINS + i], v);
    }
}

__global__ void k_findA(const u32* __restrict__ histA, u32* __restrict__ meta) {
    int n = blockIdx.x;
    const u32* h = histA + n * BINS;
    __shared__ u32 part[256];
    int t = threadIdx.x;
    u32 s = 0;
    for (int b = t * 16; b < t * 16 + 16; ++b) s += h[b];
    part[t] = s;
    __syncthreads();
    if (t == 0) {
        u32 cum = 0;
        int seg = 255;
        for (; seg > 0; --seg) {
            if (cum + part[seg] >= P_PRE) break;
            cum += part[seg];
        }
        u32 cgt = cum;
        int bA = seg * 16;
        for (int b = seg * 16 + 15; b >= seg * 16; --b) {
            if (cgt + h[b] >= P_PRE) { bA = b; break; }
            cgt += h[b];
        }
        meta[n * 16 + 0] = (u32)bA;
        meta[n * 16 + 1] = cgt;
    }
}

// ---------------- pass B: refine next 12 bits (LDS-privatized) ----------------
__global__ void k_histB(const float* __restrict__ sc, const u32* __restrict__ meta,
                        u32* __restrict__ histB) {
    int n = blockIdx.y;
    __shared__ u32 h[BINS];
    for (int i = threadIdx.x; i < BINS; i += 256) h[i] = 0;
    __syncthreads();
    u32 bA = meta[n * 16 + 0];
    const float4* s4 = (const float4*)(sc + (size_t)n * K_TOT);
    for (int i = blockIdx.x * 256 + threadIdx.x; i < K_TOT4; i += 64 * 256) {
        float4 v = s4[i];
        u32 k0 = fkey(v.x), k1 = fkey(v.y), k2 = fkey(v.z), k3 = fkey(v.w);
        if ((k0 >> 20) == bA) atomicAdd(&h[(k0 >> 8) & 0xFFFu], 1u);
        if ((k1 >> 20) == bA) atomicAdd(&h[(k1 >> 8) & 0xFFFu], 1u);
        if ((k2 >> 20) == bA) atomicAdd(&h[(k2 >> 8) & 0xFFFu], 1u);
        if ((k3 >> 20) == bA) atomicAdd(&h[(k3 >> 8) & 0xFFFu], 1u);
    }
    __syncthreads();
    for (int i = threadIdx.x; i < BINS; i += 256) {
        u32 v = h[i];
        if (v) atomicAdd(&histB[n * BINS + i], v);
    }
}

__global__ void k_findB(const u32* __restrict__ histB, u32* __restrict__ meta) {
    int n = blockIdx.x;
    const u32* h = histB + n * BINS;
    __shared__ u32 part[256];
    int t = threadIdx.x;
    u32 s = 0;
    for (int b = t * 16; b < t * 16 + 16; ++b) s += h[b];
    part[t] = s;
    __syncthreads();
    if (t == 0) {
        u32 cum = meta[n * 16 + 1];
        int seg = 255;
        for (; seg > 0; --seg) {
            if (cum + part[seg] >= P_PRE) break;
            cum += part[seg];
        }
        int bB = seg * 16;
        for (int b = seg * 16 + 15; b >= seg * 16; --b) {
            if (cum + h[b] >= P_PRE) { bB = b; break; }
            cum += h[b];
        }
        meta[n * 16 + 2] = (meta[n * 16 + 0] << 12) | (u32)bB;
    }
}

// ---------------- compaction of candidates ----------------
__global__ void k_compact(const float* __restrict__ sc, u32* __restrict__ meta,
                          u64* __restrict__ cand) {
    int n = blockIdx.y;
    int i4 = blockIdx.x * 256 + threadIdx.x;
    if (i4 >= K_TOT4) return;
    u32 thr = meta[n * 16 + 2];
    const float4* s4 = (const float4*)(sc + (size_t)n * K_TOT);
    float4 v = s4[i4];
    float vv[4] = {v.x, v.y, v.z, v.w};
    #pragma unroll
    for (int e = 0; e < 4; ++e) {
        u32 u = fkey(vv[e]);
        if ((u >> 8) >= thr) {
            u32 pos = atomicAdd(&meta[n * 16 + 3], 1u);
            if (pos < CAND_CAP) {
                int el = i4 * 4 + e;               // memory order: a*HW + h*WW + w
                int a = el / HW;
                int r = el - a * HW;               // h*WW + w
                u32 idx = (u32)(r * A_NUM + a);    // logical order (h*W + w)*A + a
                cand[n * CAND_CAP + pos] = ((u64)u << 32) | (u32)(~idx);
            }
        }
    }
}

// ---------------- single-block bitonic sort (desc), take top 6000 ----------------
__global__ void k_sortk(const u64* __restrict__ cand, const u32* __restrict__ meta,
                        u32* __restrict__ topk_idx, float* __restrict__ topk_sc) {
    int n = blockIdx.x;
    extern __shared__ u64 sk[];            // CAND_CAP entries = 64 KiB
    u32 cnt = meta[n * 16 + 3];
    if (cnt > CAND_CAP) cnt = CAND_CAP;
    for (int i = threadIdx.x; i < CAND_CAP; i += 1024)
        sk[i] = (i < (int)cnt) ? cand[n * CAND_CAP + i] : 0ull;
    __syncthreads();
    for (int k = 2; k <= CAND_CAP; k <<= 1) {
        for (int j = k >> 1; j > 0; j >>= 1) {
            for (int i = threadIdx.x; i < CAND_CAP; i += 1024) {
                int ixj = i ^ j;
                if (ixj > i) {
                    u64 a = sk[i], b = sk[ixj];
                    bool desc = ((i & k) == 0);
                    if (desc ? (a < b) : (a > b)) { sk[i] = b; sk[ixj] = a; }
                }
            }
            __syncthreads();
        }
    }
    for (int i = threadIdx.x; i < P_PRE; i += 1024) {
        u64 kk = sk[i];
        u32 idx = ~(u32)(kk & 0xFFFFFFFFull);
        u32 u = (u32)(kk >> 32);
        topk_idx[n * P_PRE + i] = idx;
        topk_sc[n * P_PRE + i] = __uint_as_float(u ^ 0x80000000u);
    }
}

// ---------------- decode + clip + valid ----------------
__global__ void k_decode(const u32* __restrict__ topk_idx,
                         const float* __restrict__ bbox, const float* __restrict__ iminfo,
                         const float* __restrict__ anchors,
                         float4* __restrict__ bbox4, u32* __restrict__ bval) {
    int t = blockIdx.x * 256 + threadIdx.x;
    if (t >= N_IMG * P_PRE) return;
    int n = t / P_PRE;
    u32 idx = topk_idx[t];
    int a = (int)(idx % A_NUM);
    int cell = (int)(idx / A_NUM);
    int w = cell % WW, h = cell / WW;
    float ax1 = anchors[a * 4 + 0] + FSTRIDE * (float)w;
    float ay1 = anchors[a * 4 + 1] + FSTRIDE * (float)h;
    float ax2 = anchors[a * 4 + 2] + FSTRIDE * (float)w;
    float ay2 = anchors[a * 4 + 3] + FSTRIDE * (float)h;
    float ws = ax2 - ax1 + 1.0f;
    float hs = ay2 - ay1 + 1.0f;
    float cx = ax1 + 0.5f * ws;
    float cy = ay1 + 0.5f * hs;
    const float* bb = bbox + (size_t)n * 4 * A_NUM * HW + h * WW + w;
    float dx = bb[(4 * a + 0) * HW];
    float dy = bb[(4 * a + 1) * HW];
    float dw = fminf(bb[(4 * a + 2) * HW], BBOX_CLIP);
    float dh = fminf(bb[(4 * a + 3) * HW], BBOX_CLIP);
    float pcx = dx * ws + cx, pcy = dy * hs + cy;
    float pw = expf(dw) * ws, ph = expf(dh) * hs;
    float x1 = pcx - 0.5f * pw;
    float y1 = pcy - 0.5f * ph;
    float x2 = pcx + 0.5f * pw - 1.0f;
    float y2 = pcy + 0.5f * ph - 1.0f;
    float im_h = iminfo[n * 3 + 0], im_w = iminfo[n * 3 + 1], iscale = iminfo[n * 3 + 2];
    x1 = fminf(fmaxf(x1, 0.0f), im_w - 1.0f);
    y1 = fminf(fmaxf(y1, 0.0f), im_h - 1.0f);
    x2 = fminf(fmaxf(x2, 0.0f), im_w - 1.0f);
    y2 = fminf(fmaxf(y2, 0.0f), im_h - 1.0f);
    float wss = x2 - x1 + 1.0f, hss = y2 - y1 + 1.0f;
    float xc = x1 + wss * 0.5f, yc = y1 + hss * 0.5f;
    float ms = MIN_SZ * iscale;
    bool valid = (wss >= ms) && (hss >= ms) && (xc < im_w) && (yc < im_h);
    float4 b; b.x = x1; b.y = y1; b.z = x2; b.w = y2;
    bbox4[t] = b;
    bval[t] = valid ? 1u : 0u;
}

// ---------------- stable partition (valid first, order preserved) ----------------
__global__ void k_partition(const float4* __restrict__ bbox4,
                            const float* __restrict__ bsc, const u32* __restrict__ bval,
                            float4* __restrict__ sbox, float* __restrict__ ssc,
                            u32* __restrict__ meta) {
    int n = blockIdx.x;
    int t = threadIdx.x;
    __shared__ u32 part[1024];
    int base = t * 6;
    u32 cnt = 0;
    if (base < P_PRE)
        for (int e = 0; e < 6; ++e) cnt += bval[n * P_PRE + base + e];
    part[t] = cnt;
    __syncthreads();
    for (int off = 1; off < 1024; off <<= 1) {
        u32 v = part[t];
        u32 add = (t >= off) ? part[t - off] : 0u;
        __syncthreads();
        part[t] = v + add;
        __syncthreads();
    }
    u32 nv = part[1023];
    u32 excl = (t == 0) ? 0u : part[t - 1];
    if (t == 0) meta[n * 16 + 4] = nv;
    if (base < P_PRE) {
        u32 vseen = excl;
        for (int e = 0; e < 6; ++e) {
            int g = base + e;
            int src = n * P_PRE + g;
            u32 dst;
            if (bval[src]) { dst = vseen; vseen++; }
            else { dst = nv + (u32)g - vseen; }
            int d = n * P_PRE + (int)dst;
            sbox[d] = bbox4[src];
            ssc[d] = bsc[src];
        }
    }
}

// ---------------- NMS suppression bitmask (upper triangle, row-major) ----------------
__global__ void k_mask(const float4* __restrict__ sbox,
                       const u32* __restrict__ meta, u64* __restrict__ mask) {
    int t = blockIdx.x * 256 + threadIdx.x;
    if (t >= N_IMG * P_PRE * NWORDS) return;
    int n = t / (P_PRE * NWORDS);
    int rem = t - n * (P_PRE * NWORDS);
    int i = rem / NWORDS;
    int c = rem - i * NWORDS;
    u32 nv = meta[n * 16 + 4];
    if ((u32)i >= nv) return;              // invalid rows never suppress / never read
    const float4* pb = sbox + n * P_PRE;
    float4 bi = pb[i];
    float ar = (bi.z - bi.x + 1.0f) * (bi.w - bi.y + 1.0f);
    int jbase = c * 64;
    int jend = min(jbase + 64, P_PRE);
    u64 m = 0;
    for (int j = max(jbase, i + 1); j < jend; ++j) {
        float4 bj = pb[j];
        float xx1 = fmaxf(bi.x, bj.x);
        float yy1 = fmaxf(bi.y, bj.y);
        float xx2 = fminf(bi.z, bj.z);
        float yy2 = fminf(bi.w, bj.w);
        float iw = fmaxf(xx2 - xx1 + 1.0f, 0.0f);
        float ih = fmaxf(yy2 - yy1 + 1.0f, 0.0f);
        float inter = iw * ih;
        float arj = (bj.z - bj.x + 1.0f) * (bj.w - bj.y + 1.0f);
        float iou = inter / (ar + arj - inter);
        if (iou > NMS_T) m |= 1ull << (j - jbase);
    }
    mask[t] = m;
}

// ---------------- per-box within-chunk suppressor bits ----------------
// selfmask[j] bit r: box (jbase + r) suppresses box j, r < j%64. Same IoU
// expression as k_mask -> bit-identical decisions.
__global__ void k_selfmask(const float4* __restrict__ sbox,
                           u64* __restrict__ selfmask) {
    int t = blockIdx.x * 256 + threadIdx.x;
    if (t >= N_IMG * P_PRE) return;
    int n = t / P_PRE;
    int j = t - n * P_PRE;
    const float4* pb = sbox + n * P_PRE;
    float4 bj = pb[j];
    float arj = (bj.z - bj.x + 1.0f) * (bj.w - bj.y + 1.0f);
    int jbase = j & ~63;
    int rend = j & 63;
    u64 m = 0;
    for (int r = 0; r < rend; ++r) {
        float4 bi = pb[jbase + r];
        float ar = (bi.z - bi.x + 1.0f) * (bi.w - bi.y + 1.0f);
        float xx1 = fmaxf(bi.x, bj.x);
        float yy1 = fmaxf(bi.y, bj.y);
        float xx2 = fminf(bi.z, bj.z);
        float yy2 = fminf(bi.w, bj.w);
        float iw = fmaxf(xx2 - xx1 + 1.0f, 0.0f);
        float ih = fmaxf(yy2 - yy1 + 1.0f, 0.0f);
        float inter = iw * ih;
        float iou = inter / (ar + arj - inter);
        if (iou > NMS_T) m |= 1ull << r;
    }
    selfmask[t] = m;
}

// ---------------- sequential greedy NMS scan (1 wave per image) ----------------
// Serial chain per kept box is now register-only: ctz -> local selfmask bit
// test -> one ballot. No shuffles, no IoU in the chain.
__global__ void k_scan(const u64* __restrict__ mask, const u64* __restrict__ selfmask,
                       u32* __restrict__ meta, u32* __restrict__ keptList) {
    int n = blockIdx.x;
    int lane = threadIdx.x;                 // 64 threads = 1 wave
    __shared__ u32 kidx[R_POST];
    u32 nv = meta[n * 16 + 4];
    int kept = 0;
    bool done = false;
    for (int c = 0; c < NWORDS && !done; ++c) {
        __syncthreads();
        int jbase = c * 64;
        int j = jbase + lane;
        u64 sm = (j < P_PRE) ? selfmask[n * P_PRE + j] : 0ull;
        u64 cur = __ballot((u32)j >= nv);   // invalid/oob start removed
        // cross-chunk suppression from previously-kept rows via mask words
        u64 acc = 0;
        for (int k = lane; k < kept; k += 64)
            acc |= mask[(size_t)((n * P_PRE + (int)kidx[k]) * NWORDS + c)];
        #pragma unroll
        for (int off = 32; off > 0; off >>= 1)
            acc |= __shfl_xor(acc, off);
        cur |= acc;
        // serial within-chunk scan using precomputed selfmask bits
        while (true) {
            u64 inv = ~cur;
            if (inv == 0ull) break;
            int b = (int)__builtin_ctzll(inv);
            if (lane == 0) {
                kidx[kept] = (u32)(jbase + b);
                keptList[n * R_POST + kept] = (u32)(jbase + b);
            }
            kept++;
            if (kept >= R_POST) { done = true; break; }
            bool sup = ((sm >> b) & 1ull) != 0ull;
            cur |= __ballot(sup);
            cur |= (1ull << b);
        }
    }
    if (lane == 0) meta[n * 16 + 5] = (u32)kept;
}

// ---------------- final output ----------------
__global__ void k_out(const float4* __restrict__ sbox, const float* __restrict__ ssc,
                      const u32* __restrict__ keptList,
                      const u32* __restrict__ meta, float* __restrict__ out) {
    int r = blockIdx.x * 256 + threadIdx.x;
    if (r >= N_IMG * R_POST) return;
    int n = r / R_POST, k = r - n * R_POST;
    float* o = out + (size_t)r * 6;
    o[0] = (float)n;                        // batch index is NOT masked in the reference
    if ((u32)k < meta[n * 16 + 5]) {
        int i = n * P_PRE + (int)keptList[n * R_POST + k];
        float4 b = sbox[i];
        o[1] = b.x; o[2] = b.y; o[3] = b.z; o[4] = b.w; o[5] = ssc[i];
    } else {
        o[1] = 0.0f; o[2] = 0.0f; o[3] = 0.0f; o[4] = 0.0f; o[5] = 0.0f;
    }
}

extern "C" void kernel_launch(void* const* d_in, const int* in_sizes, int n_in,
                              void* d_out, int out_size, void* d_ws, size_t ws_size,
                              hipStream_t stream) {
    const float* scores  = (const float*)d_in[0];
    const float* bbox    = (const float*)d_in[1];
    const float* iminfo  = (const float*)d_in[2];
    const float* anchors = (const float*)d_in[3];
    float* out = (float*)d_out;

    char* ws = (char*)d_ws;
    size_t off = 0;
    u32* histA = (u32*)(ws + off); off += (size_t)N_IMG * BINS * 4;    // 32768
    u32* histB = (u32*)(ws + off); off += (size_t)N_IMG * BINS * 4;    // 32768
    u32* meta  = (u32*)(ws + off); off += (size_t)N_IMG * 16 * 4;      // 128
    size_t zeroBytes = off;                                            // 65664
    u64* cand      = (u64*)(ws + off);   off += (size_t)N_IMG * CAND_CAP * 8;
    u32* topk_idx  = (u32*)(ws + off);   off += (size_t)N_IMG * P_PRE * 4;
    float* topk_sc = (float*)(ws + off); off += (size_t)N_IMG * P_PRE * 4;
    float4* bbox4  = (float4*)(ws + off); off += (size_t)N_IMG * P_PRE * 16;
    u32* bval  = (u32*)(ws + off);   off += (size_t)N_IMG * P_PRE * 4;
    float4* sbox = (float4*)(ws + off); off += (size_t)N_IMG * P_PRE * 16;
    float* ssc = (float*)(ws + off); off += (size_t)N_IMG * P_PRE * 4;
    u32* keptList = (u32*)(ws + off); off += (size_t)N_IMG * R_POST * 4;
    u64* selfmask = (u64*)(ws + off); off += (size_t)N_IMG * P_PRE * 8;
    u64* mask = (u64*)(ws + off);     off += (size_t)N_IMG * P_PRE * NWORDS * 8;
    (void)ws_size; (void)in_sizes; (void)n_in; (void)out_size;

    hipMemsetAsync(d_ws, 0, zeroBytes, stream);

    dim3 gHist(64, N_IMG);
    k_histA<<<gHist, 256, 0, stream>>>(scores, histA);
    k_findA<<<N_IMG, 256, 0, stream>>>(histA, meta);
    k_histB<<<gHist, 256, 0, stream>>>(scores, meta, histB);
    k_findB<<<N_IMG, 256, 0, stream>>>(histB, meta);
    dim3 gComp((K_TOT4 + 255) / 256, N_IMG);
    k_compact<<<gComp, 256, 0, stream>>>(scores, meta, cand);
    k_sortk<<<N_IMG, 1024, CAND_CAP * sizeof(u64), stream>>>(cand, meta, topk_idx, topk_sc);
    k_decode<<<(N_IMG * P_PRE + 255) / 256, 256, 0, stream>>>(topk_idx, bbox, iminfo, anchors,
                                                              bbox4, bval);
    k_partition<<<N_IMG, 1024, 0, stream>>>(bbox4, topk_sc, bval, sbox, ssc, meta);
    int gridM = (N_IMG * P_PRE * NWORDS + 255) / 256;      // 4407
    k_mask<<<gridM, 256, 0, stream>>>(sbox, meta, mask);
    k_selfmask<<<(N_IMG * P_PRE + 255) / 256, 256, 0, stream>>>(sbox, selfmask);
    k_scan<<<N_IMG, 64, 0, stream>>>(mask, selfmask, meta, keptList);
    k_out<<<(N_IMG * R_POST + 255) / 256, 256, 0, stream>>>(sbox, ssc, keptList, meta, out);
}

// Round 4
// 451.523 us; speedup vs baseline: 3.3693x; 1.1885x over previous
//
#include <hip/hip_runtime.h>
#include <stdint.h>

#define N_IMG 2
#define A_NUM 15
#define HH 200
#define WW 200
#define HW 40000          // HH*WW
#define K_TOT 600000      // A_NUM*HW
#define K_TOT4 150000     // K_TOT/4
#define P_PRE 6000
#define R_POST 1000
#define NMS_T 0.7f
#define MIN_SZ 16.0f
#define FSTRIDE 16.0f
#define BBOX_CLIP 4.135166556742356f   // log(1000/16)
#define CAND_CAP 8192
#define NWORDS 94         // ceil(6000/64)
#define BINS 4096

typedef unsigned long long u64;
typedef uint32_t u32;

// Monotone key for non-negative floats (scores are uniform [0,1)).
__device__ __forceinline__ u32 fkey(float s) {
    return __float_as_uint(s) | 0x80000000u;
}

// ---------------- pass A: 12-bit histogram + last-block findA ----------------
// grid (64, N_IMG), 256 threads.
__global__ void k_histA(const float* __restrict__ sc, u32* __restrict__ histA,
                        u32* __restrict__ meta) {
    int n = blockIdx.y;
    __shared__ u32 h[BINS];
    __shared__ u32 part[256];
    __shared__ u32 isLast;
    for (int i = threadIdx.x; i < BINS; i += 256) h[i] = 0;
    __syncthreads();
    const float4* s4 = (const float4*)(sc + (size_t)n * K_TOT);
    for (int i = blockIdx.x * 256 + threadIdx.x; i < K_TOT4; i += 64 * 256) {
        float4 v = s4[i];
        atomicAdd(&h[fkey(v.x) >> 20], 1u);
        atomicAdd(&h[fkey(v.y) >> 20], 1u);
        atomicAdd(&h[fkey(v.z) >> 20], 1u);
        atomicAdd(&h[fkey(v.w) >> 20], 1u);
    }
    __syncthreads();
    for (int i = threadIdx.x; i < BINS; i += 256) {
        u32 v = h[i];
        if (v) atomicAdd(&histA[n * BINS + i], v);
    }
    __threadfence();
    if (threadIdx.x == 0)
        isLast = (atomicAdd(&meta[6], 1u) == (u32)(64 * N_IMG - 1)) ? 1u : 0u;
    __syncthreads();
    if (!isLast) return;
    // last block: findA for both images (atomic reads for cross-XCD coherence)
    for (int im = 0; im < N_IMG; ++im) {
        u32* hh = histA + im * BINS;
        u32 s = 0;
        for (int b = threadIdx.x * 16; b < threadIdx.x * 16 + 16; ++b)
            s += atomicAdd(&hh[b], 0u);
        part[threadIdx.x] = s;
        __syncthreads();
        if (threadIdx.x == 0) {
            u32 cum = 0; int seg = 255;
            for (; seg > 0; --seg) {
                if (cum + part[seg] >= P_PRE) break;
                cum += part[seg];
            }
            u32 cgt = cum; int bA = seg * 16;
            for (int b = seg * 16 + 15; b >= seg * 16; --b) {
                u32 hb = atomicAdd(&hh[b], 0u);
                if (cgt + hb >= P_PRE) { bA = b; break; }
                cgt += hb;
            }
            meta[im * 16 + 0] = (u32)bA;
            meta[im * 16 + 1] = cgt;
        }
        __syncthreads();
    }
}

// ---------------- pass B: refine next 12 bits + last-block findB ----------------
__global__ void k_histB(const float* __restrict__ sc, u32* __restrict__ histB,
                        u32* __restrict__ meta) {
    int n = blockIdx.y;
    __shared__ u32 h[BINS];
    __shared__ u32 part[256];
    __shared__ u32 isLast;
    for (int i = threadIdx.x; i < BINS; i += 256) h[i] = 0;
    __syncthreads();
    u32 bA = meta[n * 16 + 0];
    const float4* s4 = (const float4*)(sc + (size_t)n * K_TOT);
    for (int i = blockIdx.x * 256 + threadIdx.x; i < K_TOT4; i += 64 * 256) {
        float4 v = s4[i];
        u32 k0 = fkey(v.x), k1 = fkey(v.y), k2 = fkey(v.z), k3 = fkey(v.w);
        if ((k0 >> 20) == bA) atomicAdd(&h[(k0 >> 8) & 0xFFFu], 1u);
        if ((k1 >> 20) == bA) atomicAdd(&h[(k1 >> 8) & 0xFFFu], 1u);
        if ((k2 >> 20) == bA) atomicAdd(&h[(k2 >> 8) & 0xFFFu], 1u);
        if ((k3 >> 20) == bA) atomicAdd(&h[(k3 >> 8) & 0xFFFu], 1u);
    }
    __syncthreads();
    for (int i = threadIdx.x; i < BINS; i += 256) {
        u32 v = h[i];
        if (v) atomicAdd(&histB[n * BINS + i], v);
    }
    __threadfence();
    if (threadIdx.x == 0)
        isLast = (atomicAdd(&meta[7], 1u) == (u32)(64 * N_IMG - 1)) ? 1u : 0u;
    __syncthreads();
    if (!isLast) return;
    for (int im = 0; im < N_IMG; ++im) {
        u32* hh = histB + im * BINS;
        u32 s = 0;
        for (int b = threadIdx.x * 16; b < threadIdx.x * 16 + 16; ++b)
            s += atomicAdd(&hh[b], 0u);
        part[threadIdx.x] = s;
        __syncthreads();
        if (threadIdx.x == 0) {
            u32 cum = meta[im * 16 + 1];
            int seg = 255;
            for (; seg > 0; --seg) {
                if (cum + part[seg] >= P_PRE) break;
                cum += part[seg];
            }
            int bB = seg * 16;
            for (int b = seg * 16 + 15; b >= seg * 16; --b) {
                u32 hb = atomicAdd(&hh[b], 0u);
                if (cum + hb >= P_PRE) { bB = b; break; }
                cum += hb;
            }
            meta[im * 16 + 2] = (meta[im * 16 + 0] << 12) | (u32)bB;
        }
        __syncthreads();
    }
}

// ---------------- compaction of candidates ----------------
__global__ void k_compact(const float* __restrict__ sc, u32* __restrict__ meta,
                          u64* __restrict__ cand) {
    int n = blockIdx.y;
    int i4 = blockIdx.x * 256 + threadIdx.x;
    if (i4 >= K_TOT4) return;
    u32 thr = meta[n * 16 + 2];
    const float4* s4 = (const float4*)(sc + (size_t)n * K_TOT);
    float4 v = s4[i4];
    float vv[4] = {v.x, v.y, v.z, v.w};
    #pragma unroll
    for (int e = 0; e < 4; ++e) {
        u32 u = fkey(vv[e]);
        if ((u >> 8) >= thr) {
            u32 pos = atomicAdd(&meta[n * 16 + 3], 1u);
            if (pos < CAND_CAP) {
                int el = i4 * 4 + e;               // memory order: a*HW + h*WW + w
                int a = el / HW;
                int r = el - a * HW;               // h*WW + w
                u32 idx = (u32)(r * A_NUM + a);    // logical order (h*W + w)*A + a
                cand[n * CAND_CAP + pos] = ((u64)u << 32) | (u32)(~idx);
            }
        }
    }
}

// ---------------- single-block bitonic sort (desc), take top 6000 ----------------
__global__ void k_sortk(const u64* __restrict__ cand, const u32* __restrict__ meta,
                        u32* __restrict__ topk_idx, float* __restrict__ topk_sc) {
    int n = blockIdx.x;
    extern __shared__ u64 sk[];            // CAND_CAP entries = 64 KiB
    u32 cnt = meta[n * 16 + 3];
    if (cnt > CAND_CAP) cnt = CAND_CAP;
    for (int i = threadIdx.x; i < CAND_CAP; i += 1024)
        sk[i] = (i < (int)cnt) ? cand[n * CAND_CAP + i] : 0ull;
    __syncthreads();
    for (int k = 2; k <= CAND_CAP; k <<= 1) {
        for (int j = k >> 1; j > 0; j >>= 1) {
            for (int i = threadIdx.x; i < CAND_CAP; i += 1024) {
                int ixj = i ^ j;
                if (ixj > i) {
                    u64 a = sk[i], b = sk[ixj];
                    bool desc = ((i & k) == 0);
                    if (desc ? (a < b) : (a > b)) { sk[i] = b; sk[ixj] = a; }
                }
            }
            __syncthreads();
        }
    }
    for (int i = threadIdx.x; i < P_PRE; i += 1024) {
        u64 kk = sk[i];
        u32 idx = ~(u32)(kk & 0xFFFFFFFFull);
        u32 u = (u32)(kk >> 32);
        topk_idx[n * P_PRE + i] = idx;
        topk_sc[n * P_PRE + i] = __uint_as_float(u ^ 0x80000000u);
    }
}

// ---------------- decode (in registers) + stable partition ----------------
__global__ void __launch_bounds__(1024) k_partdec(
        const u32* __restrict__ topk_idx, const float* __restrict__ topk_sc,
        const float* __restrict__ bbox, const float* __restrict__ iminfo,
        const float* __restrict__ anchors,
        float4* __restrict__ sbox, float* __restrict__ ssc, u32* __restrict__ meta) {
    int n = blockIdx.x;
    int t = threadIdx.x;
    __shared__ u32 part[1024];
    float im_h = iminfo[n * 3 + 0], im_w = iminfo[n * 3 + 1], iscale = iminfo[n * 3 + 2];
    float ms = MIN_SZ * iscale;
    float4 box[6]; float sc6[6];
    u32 vb = 0;
    int base = t * 6;
    #pragma unroll
    for (int e = 0; e < 6; ++e) {
        box[e] = make_float4(0.f, 0.f, 0.f, 0.f);
        sc6[e] = 0.f;
        int g = base + e;
        if (g < P_PRE) {
            u32 idx = topk_idx[n * P_PRE + g];
            sc6[e] = topk_sc[n * P_PRE + g];
            int a = (int)(idx % A_NUM);
            int cell = (int)(idx / A_NUM);
            int w = cell % WW, hh = cell / WW;
            float ax1 = anchors[a * 4 + 0] + FSTRIDE * (float)w;
            float ay1 = anchors[a * 4 + 1] + FSTRIDE * (float)hh;
            float ax2 = anchors[a * 4 + 2] + FSTRIDE * (float)w;
            float ay2 = anchors[a * 4 + 3] + FSTRIDE * (float)hh;
            float ws = ax2 - ax1 + 1.0f;
            float hs = ay2 - ay1 + 1.0f;
            float cx = ax1 + 0.5f * ws;
            float cy = ay1 + 0.5f * hs;
            const float* bb = bbox + (size_t)n * 4 * A_NUM * HW + hh * WW + w;
            float dx = bb[(4 * a + 0) * HW];
            float dy = bb[(4 * a + 1) * HW];
            float dw = fminf(bb[(4 * a + 2) * HW], BBOX_CLIP);
            float dh = fminf(bb[(4 * a + 3) * HW], BBOX_CLIP);
            float pcx = dx * ws + cx, pcy = dy * hs + cy;
            float pw = expf(dw) * ws, ph = expf(dh) * hs;
            float x1 = pcx - 0.5f * pw;
            float y1 = pcy - 0.5f * ph;
            float x2 = pcx + 0.5f * pw - 1.0f;
            float y2 = pcy + 0.5f * ph - 1.0f;
            x1 = fminf(fmaxf(x1, 0.0f), im_w - 1.0f);
            y1 = fminf(fmaxf(y1, 0.0f), im_h - 1.0f);
            x2 = fminf(fmaxf(x2, 0.0f), im_w - 1.0f);
            y2 = fminf(fmaxf(y2, 0.0f), im_h - 1.0f);
            float wss = x2 - x1 + 1.0f, hss = y2 - y1 + 1.0f;
            float xc = x1 + wss * 0.5f, yc = y1 + hss * 0.5f;
            bool valid = (wss >= ms) && (hss >= ms) && (xc < im_w) && (yc < im_h);
            box[e] = make_float4(x1, y1, x2, y2);
            if (valid) vb |= 1u << e;
        }
    }
    part[t] = __popc(vb);
    __syncthreads();
    for (int off = 1; off < 1024; off <<= 1) {
        u32 v = part[t];
        u32 add = (t >= off) ? part[t - off] : 0u;
        __syncthreads();
        part[t] = v + add;
        __syncthreads();
    }
    u32 nv = part[1023];
    u32 excl = (t == 0) ? 0u : part[t - 1];
    if (t == 0) meta[n * 16 + 4] = nv;
    if (base < P_PRE) {
        u32 vseen = excl;
        #pragma unroll
        for (int e = 0; e < 6; ++e) {
            int g = base + e;
            if (g < P_PRE) {
                u32 dst;
                if ((vb >> e) & 1u) { dst = vseen; vseen++; }
                else { dst = nv + (u32)g - vseen; }
                sbox[n * P_PRE + (int)dst] = box[e];
                ssc[n * P_PRE + (int)dst] = sc6[e];
            }
        }
    }
}

// ---------------- transposed suppression mask + per-box selfmask ----------------
// maskT[(n*NWORDS + c)*P_PRE + i] bit bo: box i suppresses box (c*64+bo).
// Only computed for c > chunk(i) and i < nv; other words are never read.
__global__ void k_maskT(const float4* __restrict__ sbox, const u32* __restrict__ meta,
                        u64* __restrict__ maskT, u64* __restrict__ selfmask) {
    int t = blockIdx.x * 256 + threadIdx.x;
    const int totalT = N_IMG * NWORDS * P_PRE;
    if (t < totalT) {
        int n = t / (NWORDS * P_PRE);
        int rem_ = t - n * (NWORDS * P_PRE);
        int c = rem_ / P_PRE;
        int i = rem_ - c * P_PRE;
        if (c <= (i >> 6)) return;             // lower triangle + diagonal: unused
        u32 nv = meta[n * 16 + 4];
        if ((u32)i >= nv) return;              // invalid rows never suppress
        const float4* pb = sbox + n * P_PRE;
        float4 bi = pb[i];
        float ar = (bi.z - bi.x + 1.0f) * (bi.w - bi.y + 1.0f);
        int jbase = c * 64;
        int jend = min(jbase + 64, P_PRE);
        u64 m = 0;
        for (int j = jbase; j < jend; ++j) {   // all j > i since c > i>>6
            float4 bj = pb[j];
            float xx1 = fmaxf(bi.x, bj.x);
            float yy1 = fmaxf(bi.y, bj.y);
            float xx2 = fminf(bi.z, bj.z);
            float yy2 = fminf(bi.w, bj.w);
            float iw = fmaxf(xx2 - xx1 + 1.0f, 0.0f);
            float ih = fmaxf(yy2 - yy1 + 1.0f, 0.0f);
            float inter = iw * ih;
            float arj = (bj.z - bj.x + 1.0f) * (bj.w - bj.y + 1.0f);
            float iou = inter / (ar + arj - inter);
            if (iou > NMS_T) m |= 1ull << (j - jbase);
        }
        maskT[(size_t)(n * NWORDS + c) * P_PRE + i] = m;
    } else {
        int t2 = t - totalT;
        if (t2 >= N_IMG * P_PRE) return;
        int n = t2 / P_PRE;
        int j = t2 - n * P_PRE;
        const float4* pb = sbox + n * P_PRE;
        float4 bj = pb[j];
        float arj = (bj.z - bj.x + 1.0f) * (bj.w - bj.y + 1.0f);
        int jbase = j & ~63;
        int rend = j & 63;
        u64 m = 0;
        for (int r = 0; r < rend; ++r) {
            float4 bi = pb[jbase + r];
            float ar = (bi.z - bi.x + 1.0f) * (bi.w - bi.y + 1.0f);
            float xx1 = fmaxf(bi.x, bj.x);
            float yy1 = fmaxf(bi.y, bj.y);
            float xx2 = fminf(bi.z, bj.z);
            float yy2 = fminf(bi.w, bj.w);
            float iw = fmaxf(xx2 - xx1 + 1.0f, 0.0f);
            float ih = fmaxf(yy2 - yy1 + 1.0f, 0.0f);
            float inter = iw * ih;
            float iou = inter / (ar + arj - inter);
            if (iou > NMS_T) m |= 1ull << r;
        }
        selfmask[t2] = m;
    }
}

// ---------------- greedy NMS scan: forward-scatter, branchless bit loop ----------------
// 1 wave per image. Lane l owns removed-words for columns l and l+64 in registers.
__global__ void __launch_bounds__(64) k_scan(
        const u64* __restrict__ maskT, const u64* __restrict__ selfmask,
        const float4* __restrict__ sbox, const float* __restrict__ ssc,
        const u32* __restrict__ meta, float* __restrict__ out) {
    int n = blockIdx.x;
    int lane = threadIdx.x;
    __shared__ u32 kidx[R_POST];
    u32 nv = meta[n * 16 + 4];
    const u64* mT = maskT + (size_t)n * NWORDS * P_PRE;
    const u64* smk = selfmask + (size_t)n * P_PRE;
    int c0 = lane, c1 = lane + 64;
    // init: bits j >= nv removed
    u64 rem0, rem1;
    {
        int b0 = c0 * 64;
        rem0 = ((u32)b0 >= nv) ? ~0ull : ((nv - b0 >= 64) ? 0ull : ((~0ull) << (nv - b0)));
        if (c1 < NWORDS) {
            int b1 = c1 * 64;
            rem1 = ((u32)b1 >= nv) ? ~0ull : ((nv - b1 >= 64) ? 0ull : ((~0ull) << (nv - b1)));
        } else rem1 = 0ull;
    }
    const u64* col0 = mT + (size_t)c0 * P_PRE;
    const u64* col1 = mT + (size_t)((c1 < NWORDS) ? c1 : 0) * P_PRE;  // clamped; junk never read
    int kept = 0;
    u64 sm_next = smk[lane];                       // chunk 0 prefetch
    for (int c = 0; c < NWORDS; ++c) {
        u64 sm = sm_next;
        int ni = (c + 1) * 64 + lane;
        sm_next = ((c + 1) < NWORDS && ni < P_PRE) ? smk[ni] : 0ull;
        u64 wsel = (c < 64) ? rem0 : rem1;
        u64 cur = __shfl(wsel, c & 63);            // broadcast from owner lane
        if (cur != ~0ull) {
            int keptBase = kept;
            u64 newkept = 0;
            #pragma unroll
            for (int b = 0; b < 64; ++b) {
                u64 supw = __ballot(((sm >> b) & 1ull) != 0ull);
                u64 aliveM = (u64)0 - ((((~cur) >> b) & 1ull) & (u64)(kept < R_POST));
                cur |= supw & aliveM;
                newkept |= (1ull << b) & aliveM;
                kept += (int)(aliveM & 1ull);
            }
            if (newkept) {
                int jbase = c * 64;
                if ((newkept >> lane) & 1ull) {
                    u64 below = newkept & ((1ull << lane) - 1ull);
                    kidx[keptBase + __popcll(below)] = (u32)(jbase + lane);
                }
                // forward scatter: OR kept rows' mask words into owned columns.
                // 8 rows per batch -> independent, pipelined loads.
                u64 km = newkept;
                while (km) {
                    int r0 = (int)__builtin_ctzll(km); km &= km - 1;
                    int r1 = km ? (int)__builtin_ctzll(km) : r0; km &= km - 1;
                    int r2 = km ? (int)__builtin_ctzll(km) : r0; km &= km - 1;
                    int r3 = km ? (int)__builtin_ctzll(km) : r0; km &= km - 1;
                    int r4 = km ? (int)__builtin_ctzll(km) : r0; km &= km - 1;
                    int r5 = km ? (int)__builtin_ctzll(km) : r0; km &= km - 1;
                    int r6 = km ? (int)__builtin_ctzll(km) : r0; km &= km - 1;
                    int r7 = km ? (int)__builtin_ctzll(km) : r0; km &= km - 1;
                    u64 t0 = col0[jbase + r0], t1 = col0[jbase + r1];
                    u64 t2 = col0[jbase + r2], t3 = col0[jbase + r3];
                    u64 t4 = col0[jbase + r4], t5 = col0[jbase + r5];
                    u64 t6 = col0[jbase + r6], t7 = col0[jbase + r7];
                    u64 u0 = col1[jbase + r0], u1 = col1[jbase + r1];
                    u64 u2 = col1[jbase + r2], u3 = col1[jbase + r3];
                    u64 u4 = col1[jbase + r4], u5 = col1[jbase + r5];
                    u64 u6 = col1[jbase + r6], u7 = col1[jbase + r7];
                    rem0 |= t0 | t1 | t2 | t3 | t4 | t5 | t6 | t7;
                    rem1 |= u0 | u1 | u2 | u3 | u4 | u5 | u6 | u7;
                }
                // stale/garbage ORs only land in already-consumed columns (<= c)
                // or columns >= NWORDS (never broadcast) -> harmless.
            }
        }
        if (kept >= R_POST) break;
    }
    __syncthreads();
    // fused output
    for (int r = lane; r < R_POST; r += 64) {
        float4 b = make_float4(0.f, 0.f, 0.f, 0.f);
        float s = 0.f;
        if (r < kept) {
            u32 i = kidx[r];
            b = sbox[n * P_PRE + (int)i];
            s = ssc[n * P_PRE + (int)i];
        }
        float* o = out + (size_t)(n * R_POST + r) * 6;
        o[0] = (float)n;                   // batch index NOT masked in reference
        o[1] = b.x; o[2] = b.y; o[3] = b.z; o[4] = b.w; o[5] = s;
    }
}

extern "C" void kernel_launch(void* const* d_in, const int* in_sizes, int n_in,
                              void* d_out, int out_size, void* d_ws, size_t ws_size,
                              hipStream_t stream) {
    const float* scores  = (const float*)d_in[0];
    const float* bbox    = (const float*)d_in[1];
    const float* iminfo  = (const float*)d_in[2];
    const float* anchors = (const float*)d_in[3];
    float* out = (float*)d_out;

    char* ws = (char*)d_ws;
    size_t off = 0;
    u32* histA = (u32*)(ws + off); off += (size_t)N_IMG * BINS * 4;    // 32768
    u32* histB = (u32*)(ws + off); off += (size_t)N_IMG * BINS * 4;    // 32768
    u32* meta  = (u32*)(ws + off); off += (size_t)N_IMG * 16 * 4;      // 128
    size_t zeroBytes = off;                                            // 65664
    u64* cand      = (u64*)(ws + off);   off += (size_t)N_IMG * CAND_CAP * 8;
    u32* topk_idx  = (u32*)(ws + off);   off += (size_t)N_IMG * P_PRE * 4;
    float* topk_sc = (float*)(ws + off); off += (size_t)N_IMG * P_PRE * 4;
    float4* sbox = (float4*)(ws + off);  off += (size_t)N_IMG * P_PRE * 16;
    float* ssc = (float*)(ws + off);     off += (size_t)N_IMG * P_PRE * 4;
    u64* selfmask = (u64*)(ws + off);    off += (size_t)N_IMG * P_PRE * 8;
    u64* maskT = (u64*)(ws + off);       off += (size_t)N_IMG * NWORDS * P_PRE * 8;
    (void)ws_size; (void)in_sizes; (void)n_in; (void)out_size;

    hipMemsetAsync(d_ws, 0, zeroBytes, stream);

    dim3 gHist(64, N_IMG);
    k_histA<<<gHist, 256, 0, stream>>>(scores, histA, meta);
    k_histB<<<gHist, 256, 0, stream>>>(scores, histB, meta);
    dim3 gComp((K_TOT4 + 255) / 256, N_IMG);
    k_compact<<<gComp, 256, 0, stream>>>(scores, meta, cand);
    k_sortk<<<N_IMG, 1024, CAND_CAP * sizeof(u64), stream>>>(cand, meta, topk_idx, topk_sc);
    k_partdec<<<N_IMG, 1024, 0, stream>>>(topk_idx, topk_sc, bbox, iminfo, anchors,
                                          sbox, ssc, meta);
    int totalMask = N_IMG * NWORDS * P_PRE + N_IMG * P_PRE;
    k_maskT<<<(totalMask + 255) / 256, 256, 0, stream>>>(sbox, meta, maskT, selfmask);
    k_scan<<<N_IMG, 64, 0, stream>>>(maskT, selfmask, sbox, ssc, meta, out);
}

// Round 5
// 417.434 us; speedup vs baseline: 3.6444x; 1.0817x over previous
//
#include <hip/hip_runtime.h>
#include <stdint.h>

#define N_IMG 2
#define A_NUM 15
#define HH 200
#define WW 200
#define HW 40000          // HH*WW
#define K_TOT 600000      // A_NUM*HW
#define K_TOT4 150000     // K_TOT/4
#define P_PRE 6000
#define R_POST 1000
#define NMS_T 0.7f
#define MIN_SZ 16.0f
#define FSTRIDE 16.0f
#define BBOX_CLIP 4.135166556742356f   // log(1000/16)
#define CAND_CAP 8192
#define NWORDS 94         // ceil(6000/64)
#define BINS 4096

typedef unsigned long long u64;
typedef uint32_t u32;

// Monotone key for non-negative floats (scores are uniform [0,1)).
__device__ __forceinline__ u32 fkey(float s) {
    return __float_as_uint(s) | 0x80000000u;
}

// ---------------- pass A: 12-bit histogram + last-block findA ----------------
// grid (64, N_IMG), 256 threads.
__global__ void k_histA(const float* __restrict__ sc, u32* __restrict__ histA,
                        u32* __restrict__ meta) {
    int n = blockIdx.y;
    __shared__ u32 h[BINS];
    __shared__ u32 part[256];
    __shared__ u32 isLast;
    for (int i = threadIdx.x; i < BINS; i += 256) h[i] = 0;
    __syncthreads();
    const float4* s4 = (const float4*)(sc + (size_t)n * K_TOT);
    for (int i = blockIdx.x * 256 + threadIdx.x; i < K_TOT4; i += 64 * 256) {
        float4 v = s4[i];
        atomicAdd(&h[fkey(v.x) >> 20], 1u);
        atomicAdd(&h[fkey(v.y) >> 20], 1u);
        atomicAdd(&h[fkey(v.z) >> 20], 1u);
        atomicAdd(&h[fkey(v.w) >> 20], 1u);
    }
    __syncthreads();
    for (int i = threadIdx.x; i < BINS; i += 256) {
        u32 v = h[i];
        if (v) atomicAdd(&histA[n * BINS + i], v);
    }
    __threadfence();
    if (threadIdx.x == 0)
        isLast = (atomicAdd(&meta[6], 1u) == (u32)(64 * N_IMG - 1)) ? 1u : 0u;
    __syncthreads();
    if (!isLast) return;
    // last block: findA for both images (atomic reads for cross-XCD coherence)
    for (int im = 0; im < N_IMG; ++im) {
        u32* hh = histA + im * BINS;
        u32 s = 0;
        for (int b = threadIdx.x * 16; b < threadIdx.x * 16 + 16; ++b)
            s += atomicAdd(&hh[b], 0u);
        part[threadIdx.x] = s;
        __syncthreads();
        if (threadIdx.x == 0) {
            u32 cum = 0; int seg = 255;
            for (; seg > 0; --seg) {
                if (cum + part[seg] >= P_PRE) break;
                cum += part[seg];
            }
            u32 cgt = cum; int bA = seg * 16;
            for (int b = seg * 16 + 15; b >= seg * 16; --b) {
                u32 hb = atomicAdd(&hh[b], 0u);
                if (cgt + hb >= P_PRE) { bA = b; break; }
                cgt += hb;
            }
            meta[im * 16 + 0] = (u32)bA;
            meta[im * 16 + 1] = cgt;
        }
        __syncthreads();
    }
}

// ---------------- pass B: refine next 12 bits + last-block findB ----------------
__global__ void k_histB(const float* __restrict__ sc, u32* __restrict__ histB,
                        u32* __restrict__ meta) {
    int n = blockIdx.y;
    __shared__ u32 h[BINS];
    __shared__ u32 part[256];
    __shared__ u32 isLast;
    for (int i = threadIdx.x; i < BINS; i += 256) h[i] = 0;
    __syncthreads();
    u32 bA = meta[n * 16 + 0];
    const float4* s4 = (const float4*)(sc + (size_t)n * K_TOT);
    for (int i = blockIdx.x * 256 + threadIdx.x; i < K_TOT4; i += 64 * 256) {
        float4 v = s4[i];
        u32 k0 = fkey(v.x), k1 = fkey(v.y), k2 = fkey(v.z), k3 = fkey(v.w);
        if ((k0 >> 20) == bA) atomicAdd(&h[(k0 >> 8) & 0xFFFu], 1u);
        if ((k1 >> 20) == bA) atomicAdd(&h[(k1 >> 8) & 0xFFFu], 1u);
        if ((k2 >> 20) == bA) atomicAdd(&h[(k2 >> 8) & 0xFFFu], 1u);
        if ((k3 >> 20) == bA) atomicAdd(&h[(k3 >> 8) & 0xFFFu], 1u);
    }
    __syncthreads();
    for (int i = threadIdx.x; i < BINS; i += 256) {
        u32 v = h[i];
        if (v) atomicAdd(&histB[n * BINS + i], v);
    }
    __threadfence();
    if (threadIdx.x == 0)
        isLast = (atomicAdd(&meta[7], 1u) == (u32)(64 * N_IMG - 1)) ? 1u : 0u;
    __syncthreads();
    if (!isLast) return;
    for (int im = 0; im < N_IMG; ++im) {
        u32* hh = histB + im * BINS;
        u32 s = 0;
        for (int b = threadIdx.x * 16; b < threadIdx.x * 16 + 16; ++b)
            s += atomicAdd(&hh[b], 0u);
        part[threadIdx.x] = s;
        __syncthreads();
        if (threadIdx.x == 0) {
            u32 cum = meta[im * 16 + 1];
            int seg = 255;
            for (; seg > 0; --seg) {
                if (cum + part[seg] >= P_PRE) break;
                cum += part[seg];
            }
            int bB = seg * 16;
            for (int b = seg * 16 + 15; b >= seg * 16; --b) {
                u32 hb = atomicAdd(&hh[b], 0u);
                if (cum + hb >= P_PRE) { bB = b; break; }
                cum += hb;
            }
            meta[im * 16 + 2] = (meta[im * 16 + 0] << 12) | (u32)bB;
        }
        __syncthreads();
    }
}

// ---------------- compaction of candidates ----------------
__global__ void k_compact(const float* __restrict__ sc, u32* __restrict__ meta,
                          u64* __restrict__ cand) {
    int n = blockIdx.y;
    int i4 = blockIdx.x * 256 + threadIdx.x;
    if (i4 >= K_TOT4) return;
    u32 thr = meta[n * 16 + 2];
    const float4* s4 = (const float4*)(sc + (size_t)n * K_TOT);
    float4 v = s4[i4];
    float vv[4] = {v.x, v.y, v.z, v.w};
    #pragma unroll
    for (int e = 0; e < 4; ++e) {
        u32 u = fkey(vv[e]);
        if ((u >> 8) >= thr) {
            u32 pos = atomicAdd(&meta[n * 16 + 3], 1u);
            if (pos < CAND_CAP) {
                int el = i4 * 4 + e;               // memory order: a*HW + h*WW + w
                int a = el / HW;
                int r = el - a * HW;               // h*WW + w
                u32 idx = (u32)(r * A_NUM + a);    // logical order (h*W + w)*A + a
                cand[n * CAND_CAP + pos] = ((u64)u << 32) | (u32)(~idx);
            }
        }
    }
}

// ---------------- exact rank (counting) sort, replaces bitonic ----------------
// Keys unique (idx embedded) -> rank = #keys strictly greater = stable desc pos.
// grid (32, N_IMG) x 256. Each block stages all keys in LDS (broadcast reads).
__global__ void __launch_bounds__(256) k_rank(const u64* __restrict__ cand,
                                              const u32* __restrict__ meta,
                                              u32* __restrict__ topk_idx,
                                              float* __restrict__ topk_sc) {
    int n = blockIdx.y;
    u32 cnt = meta[n * 16 + 3];
    if (cnt > CAND_CAP) cnt = CAND_CAP;
    if ((u32)(blockIdx.x * 256) >= cnt) return;    // block entirely past cnt
    __shared__ u64 sk[CAND_CAP];                   // 64 KiB
    int cntPad = (int)((cnt + 7u) & ~7u);
    const u64* cn = cand + (size_t)n * CAND_CAP;
    for (int i = threadIdx.x; i < cntPad; i += 256)
        sk[i] = (i < (int)cnt) ? cn[i] : 0ull;     // pad 0 < any real key (bit63 set)
    __syncthreads();
    int myi = blockIdx.x * 256 + threadIdx.x;
    if (myi >= (int)cnt) return;
    u64 mykey = sk[myi];
    int rank = 0;
    for (int j = 0; j < cntPad; j += 8) {
        u64 k0 = sk[j + 0], k1 = sk[j + 1], k2 = sk[j + 2], k3 = sk[j + 3];
        u64 k4 = sk[j + 4], k5 = sk[j + 5], k6 = sk[j + 6], k7 = sk[j + 7];
        rank += (int)(k0 > mykey) + (int)(k1 > mykey)
              + (int)(k2 > mykey) + (int)(k3 > mykey)
              + (int)(k4 > mykey) + (int)(k5 > mykey)
              + (int)(k6 > mykey) + (int)(k7 > mykey);
    }
    if (rank < P_PRE) {
        topk_idx[n * P_PRE + rank] = ~(u32)(mykey & 0xFFFFFFFFull);
        topk_sc[n * P_PRE + rank] = __uint_as_float((u32)(mykey >> 32) ^ 0x80000000u);
    }
}

// ---------------- decode (in registers) + stable partition ----------------
__global__ void __launch_bounds__(1024) k_partdec(
        const u32* __restrict__ topk_idx, const float* __restrict__ topk_sc,
        const float* __restrict__ bbox, const float* __restrict__ iminfo,
        const float* __restrict__ anchors,
        float4* __restrict__ sbox, float* __restrict__ ssc, u32* __restrict__ meta) {
    int n = blockIdx.x;
    int t = threadIdx.x;
    __shared__ u32 part[1024];
    float im_h = iminfo[n * 3 + 0], im_w = iminfo[n * 3 + 1], iscale = iminfo[n * 3 + 2];
    float ms = MIN_SZ * iscale;
    float4 box[6]; float sc6[6];
    u32 vb = 0;
    int base = t * 6;
    #pragma unroll
    for (int e = 0; e < 6; ++e) {
        box[e] = make_float4(0.f, 0.f, 0.f, 0.f);
        sc6[e] = 0.f;
        int g = base + e;
        if (g < P_PRE) {
            u32 idx = topk_idx[n * P_PRE + g];
            sc6[e] = topk_sc[n * P_PRE + g];
            int a = (int)(idx % A_NUM);
            int cell = (int)(idx / A_NUM);
            int w = cell % WW, hh = cell / WW;
            float ax1 = anchors[a * 4 + 0] + FSTRIDE * (float)w;
            float ay1 = anchors[a * 4 + 1] + FSTRIDE * (float)hh;
            float ax2 = anchors[a * 4 + 2] + FSTRIDE * (float)w;
            float ay2 = anchors[a * 4 + 3] + FSTRIDE * (float)hh;
            float ws = ax2 - ax1 + 1.0f;
            float hs = ay2 - ay1 + 1.0f;
            float cx = ax1 + 0.5f * ws;
            float cy = ay1 + 0.5f * hs;
            const float* bb = bbox + (size_t)n * 4 * A_NUM * HW + hh * WW + w;
            float dx = bb[(4 * a + 0) * HW];
            float dy = bb[(4 * a + 1) * HW];
            float dw = fminf(bb[(4 * a + 2) * HW], BBOX_CLIP);
            float dh = fminf(bb[(4 * a + 3) * HW], BBOX_CLIP);
            float pcx = dx * ws + cx, pcy = dy * hs + cy;
            float pw = expf(dw) * ws, ph = expf(dh) * hs;
            float x1 = pcx - 0.5f * pw;
            float y1 = pcy - 0.5f * ph;
            float x2 = pcx + 0.5f * pw - 1.0f;
            float y2 = pcy + 0.5f * ph - 1.0f;
            x1 = fminf(fmaxf(x1, 0.0f), im_w - 1.0f);
            y1 = fminf(fmaxf(y1, 0.0f), im_h - 1.0f);
            x2 = fminf(fmaxf(x2, 0.0f), im_w - 1.0f);
            y2 = fminf(fmaxf(y2, 0.0f), im_h - 1.0f);
            float wss = x2 - x1 + 1.0f, hss = y2 - y1 + 1.0f;
            float xc = x1 + wss * 0.5f, yc = y1 + hss * 0.5f;
            bool valid = (wss >= ms) && (hss >= ms) && (xc < im_w) && (yc < im_h);
            box[e] = make_float4(x1, y1, x2, y2);
            if (valid) vb |= 1u << e;
        }
    }
    part[t] = __popc(vb);
    __syncthreads();
    for (int off = 1; off < 1024; off <<= 1) {
        u32 v = part[t];
        u32 add = (t >= off) ? part[t - off] : 0u;
        __syncthreads();
        part[t] = v + add;
        __syncthreads();
    }
    u32 nv = part[1023];
    u32 excl = (t == 0) ? 0u : part[t - 1];
    if (t == 0) meta[n * 16 + 4] = nv;
    if (base < P_PRE) {
        u32 vseen = excl;
        #pragma unroll
        for (int e = 0; e < 6; ++e) {
            int g = base + e;
            if (g < P_PRE) {
                u32 dst;
                if ((vb >> e) & 1u) { dst = vseen; vseen++; }
                else { dst = nv + (u32)g - vseen; }
                sbox[n * P_PRE + (int)dst] = box[e];
                ssc[n * P_PRE + (int)dst] = sc6[e];
            }
        }
    }
}

// ---------------- transposed suppression mask + per-box selfmask ----------------
// maskT[(n*NWORDS + c)*P_PRE + i] bit bo: box i suppresses box (c*64+bo).
// Only computed for c > chunk(i) and i < nv; other words are never read.
__global__ void k_maskT(const float4* __restrict__ sbox, const u32* __restrict__ meta,
                        u64* __restrict__ maskT, u64* __restrict__ selfmask) {
    int t = blockIdx.x * 256 + threadIdx.x;
    const int totalT = N_IMG * NWORDS * P_PRE;
    if (t < totalT) {
        int n = t / (NWORDS * P_PRE);
        int rem_ = t - n * (NWORDS * P_PRE);
        int c = rem_ / P_PRE;
        int i = rem_ - c * P_PRE;
        if (c <= (i >> 6)) return;             // lower triangle + diagonal: unused
        u32 nv = meta[n * 16 + 4];
        if ((u32)i >= nv) return;              // invalid rows never suppress
        const float4* pb = sbox + n * P_PRE;
        float4 bi = pb[i];
        float ar = (bi.z - bi.x + 1.0f) * (bi.w - bi.y + 1.0f);
        int jbase = c * 64;
        int jend = min(jbase + 64, P_PRE);
        u64 m = 0;
        for (int j = jbase; j < jend; ++j) {   // all j > i since c > i>>6
            float4 bj = pb[j];
            float xx1 = fmaxf(bi.x, bj.x);
            float yy1 = fmaxf(bi.y, bj.y);
            float xx2 = fminf(bi.z, bj.z);
            float yy2 = fminf(bi.w, bj.w);
            float iw = fmaxf(xx2 - xx1 + 1.0f, 0.0f);
            float ih = fmaxf(yy2 - yy1 + 1.0f, 0.0f);
            float inter = iw * ih;
            float arj = (bj.z - bj.x + 1.0f) * (bj.w - bj.y + 1.0f);
            float iou = inter / (ar + arj - inter);
            if (iou > NMS_T) m |= 1ull << (j - jbase);
        }
        maskT[(size_t)(n * NWORDS + c) * P_PRE + i] = m;
    } else {
        int t2 = t - totalT;
        if (t2 >= N_IMG * P_PRE) return;
        int n = t2 / P_PRE;
        int j = t2 - n * P_PRE;
        const float4* pb = sbox + n * P_PRE;
        float4 bj = pb[j];
        float arj = (bj.z - bj.x + 1.0f) * (bj.w - bj.y + 1.0f);
        int jbase = j & ~63;
        int rend = j & 63;
        u64 m = 0;
        for (int r = 0; r < rend; ++r) {
            float4 bi = pb[jbase + r];
            float ar = (bi.z - bi.x + 1.0f) * (bi.w - bi.y + 1.0f);
            float xx1 = fmaxf(bi.x, bj.x);
            float yy1 = fmaxf(bi.y, bj.y);
            float xx2 = fminf(bi.z, bj.z);
            float yy2 = fminf(bi.w, bj.w);
            float iw = fmaxf(xx2 - xx1 + 1.0f, 0.0f);
            float ih = fmaxf(yy2 - yy1 + 1.0f, 0.0f);
            float inter = iw * ih;
            float iou = inter / (ar + arj - inter);
            if (iou > NMS_T) m |= 1ull << r;
        }
        selfmask[t2] = m;
    }
}

// ---------------- greedy NMS scan: forward-scatter, branchless bit loop ----------------
// 1 wave per image. Lane l owns removed-words for columns l and l+64 in registers.
__global__ void __launch_bounds__(64) k_scan(
        const u64* __restrict__ maskT, const u64* __restrict__ selfmask,
        const float4* __restrict__ sbox, const float* __restrict__ ssc,
        const u32* __restrict__ meta, float* __restrict__ out) {
    int n = blockIdx.x;
    int lane = threadIdx.x;
    __shared__ u32 kidx[R_POST];
    u32 nv = meta[n * 16 + 4];
    const u64* mT = maskT + (size_t)n * NWORDS * P_PRE;
    const u64* smk = selfmask + (size_t)n * P_PRE;
    int c0 = lane, c1 = lane + 64;
    // init: bits j >= nv removed
    u64 rem0, rem1;
    {
        int b0 = c0 * 64;
        rem0 = ((u32)b0 >= nv) ? ~0ull : ((nv - b0 >= 64) ? 0ull : ((~0ull) << (nv - b0)));
        if (c1 < NWORDS) {
            int b1 = c1 * 64;
            rem1 = ((u32)b1 >= nv) ? ~0ull : ((nv - b1 >= 64) ? 0ull : ((~0ull) << (nv - b1)));
        } else rem1 = 0ull;
    }
    const u64* col0 = mT + (size_t)c0 * P_PRE;
    const u64* col1 = mT + (size_t)((c1 < NWORDS) ? c1 : 0) * P_PRE;  // clamped; junk never read
    int kept = 0;
    u64 sm_next = smk[lane];                       // chunk 0 prefetch
    for (int c = 0; c < NWORDS; ++c) {
        u64 sm = sm_next;
        int ni = (c + 1) * 64 + lane;
        sm_next = ((c + 1) < NWORDS && ni < P_PRE) ? smk[ni] : 0ull;
        u64 wsel = (c < 64) ? rem0 : rem1;
        u64 cur = __shfl(wsel, c & 63);            // broadcast from owner lane
        if (cur != ~0ull) {
            int keptBase = kept;
            u64 newkept = 0;
            #pragma unroll
            for (int b = 0; b < 64; ++b) {
                u64 supw = __ballot(((sm >> b) & 1ull) != 0ull);
                u64 aliveM = (u64)0 - ((((~cur) >> b) & 1ull) & (u64)(kept < R_POST));
                cur |= supw & aliveM;
                newkept |= (1ull << b) & aliveM;
                kept += (int)(aliveM & 1ull);
            }
            if (newkept) {
                int jbase = c * 64;
                if ((newkept >> lane) & 1ull) {
                    u64 below = newkept & ((1ull << lane) - 1ull);
                    kidx[keptBase + __popcll(below)] = (u32)(jbase + lane);
                }
                // forward scatter: OR kept rows' mask words into owned columns.
                // 8 rows per batch -> independent, pipelined loads.
                u64 km = newkept;
                while (km) {
                    int r0 = (int)__builtin_ctzll(km); km &= km - 1;
                    int r1 = km ? (int)__builtin_ctzll(km) : r0; km &= km - 1;
                    int r2 = km ? (int)__builtin_ctzll(km) : r0; km &= km - 1;
                    int r3 = km ? (int)__builtin_ctzll(km) : r0; km &= km - 1;
                    int r4 = km ? (int)__builtin_ctzll(km) : r0; km &= km - 1;
                    int r5 = km ? (int)__builtin_ctzll(km) : r0; km &= km - 1;
                    int r6 = km ? (int)__builtin_ctzll(km) : r0; km &= km - 1;
                    int r7 = km ? (int)__builtin_ctzll(km) : r0; km &= km - 1;
                    u64 t0 = col0[jbase + r0], t1 = col0[jbase + r1];
                    u64 t2 = col0[jbase + r2], t3 = col0[jbase + r3];
                    u64 t4 = col0[jbase + r4], t5 = col0[jbase + r5];
                    u64 t6 = col0[jbase + r6], t7 = col0[jbase + r7];
                    u64 u0 = col1[jbase + r0], u1 = col1[jbase + r1];
                    u64 u2 = col1[jbase + r2], u3 = col1[jbase + r3];
                    u64 u4 = col1[jbase + r4], u5 = col1[jbase + r5];
                    u64 u6 = col1[jbase + r6], u7 = col1[jbase + r7];
                    rem0 |= t0 | t1 | t2 | t3 | t4 | t5 | t6 | t7;
                    rem1 |= u0 | u1 | u2 | u3 | u4 | u5 | u6 | u7;
                }
                // stale/garbage ORs only land in already-consumed columns (<= c)
                // or columns >= NWORDS (never broadcast) -> harmless.
            }
        }
        if (kept >= R_POST) break;
    }
    __syncthreads();
    // fused output
    for (int r = lane; r < R_POST; r += 64) {
        float4 b = make_float4(0.f, 0.f, 0.f, 0.f);
        float s = 0.f;
        if (r < kept) {
            u32 i = kidx[r];
            b = sbox[n * P_PRE + (int)i];
            s = ssc[n * P_PRE + (int)i];
        }
        float* o = out + (size_t)(n * R_POST + r) * 6;
        o[0] = (float)n;                   // batch index NOT masked in reference
        o[1] = b.x; o[2] = b.y; o[3] = b.z; o[4] = b.w; o[5] = s;
    }
}

extern "C" void kernel_launch(void* const* d_in, const int* in_sizes, int n_in,
                              void* d_out, int out_size, void* d_ws, size_t ws_size,
                              hipStream_t stream) {
    const float* scores  = (const float*)d_in[0];
    const float* bbox    = (const float*)d_in[1];
    const float* iminfo  = (const float*)d_in[2];
    const float* anchors = (const float*)d_in[3];
    float* out = (float*)d_out;

    char* ws = (char*)d_ws;
    size_t off = 0;
    u32* histA = (u32*)(ws + off); off += (size_t)N_IMG * BINS * 4;    // 32768
    u32* histB = (u32*)(ws + off); off += (size_t)N_IMG * BINS * 4;    // 32768
    u32* meta  = (u32*)(ws + off); off += (size_t)N_IMG * 16 * 4;      // 128
    size_t zeroBytes = off;                                            // 65664
    u64* cand      = (u64*)(ws + off);   off += (size_t)N_IMG * CAND_CAP * 8;
    u32* topk_idx  = (u32*)(ws + off);   off += (size_t)N_IMG * P_PRE * 4;
    float* topk_sc = (float*)(ws + off); off += (size_t)N_IMG * P_PRE * 4;
    float4* sbox = (float4*)(ws + off);  off += (size_t)N_IMG * P_PRE * 16;
    float* ssc = (float*)(ws + off);     off += (size_t)N_IMG * P_PRE * 4;
    u64* selfmask = (u64*)(ws + off);    off += (size_t)N_IMG * P_PRE * 8;
    u64* maskT = (u64*)(ws + off);       off += (size_t)N_IMG * NWORDS * P_PRE * 8;
    (void)ws_size; (void)in_sizes; (void)n_in; (void)out_size;

    hipMemsetAsync(d_ws, 0, zeroBytes, stream);

    dim3 gHist(64, N_IMG);
    k_histA<<<gHist, 256, 0, stream>>>(scores, histA, meta);
    k_histB<<<gHist, 256, 0, stream>>>(scores, histB, meta);
    dim3 gComp((K_TOT4 + 255) / 256, N_IMG);
    k_compact<<<gComp, 256, 0, stream>>>(scores, meta, cand);
    dim3 gRank(CAND_CAP / 256, N_IMG);
    k_rank<<<gRank, 256, 0, stream>>>(cand, meta, topk_idx, topk_sc);
    k_partdec<<<N_IMG, 1024, 0, stream>>>(topk_idx, topk_sc, bbox, iminfo, anchors,
                                          sbox, ssc, meta);
    int totalMask = N_IMG * NWORDS * P_PRE + N_IMG * P_PRE;
    k_maskT<<<(totalMask + 255) / 256, 256, 0, stream>>>(sbox, meta, maskT, selfmask);
    k_scan<<<N_IMG, 64, 0, stream>>>(maskT, selfmask, sbox, ssc, meta, out);
}